// Round 1
// 876.559 us; speedup vs baseline: 1.1980x; 1.1980x over previous
//
#include <hip/hip_runtime.h>

// Problem constants
#define B_   64
#define T_   512
#define F_   512
#define F2_  256
#define F4_  128
#define R_   32768      // B*T slots
#define RM_  131072     // R*4 move rows

typedef __attribute__((ext_vector_type(8))) short bf16x8;
typedef __attribute__((ext_vector_type(4))) float f32x4;

// ---------------------------------------------------------------------------
// split fp32 -> (hi, lo) bf16 with RNE; a ~= hi + lo to ~16-17 mantissa bits
// ---------------------------------------------------------------------------
__device__ __forceinline__ void split_bf16(float a, unsigned short& h, unsigned short& l)
{
    unsigned x  = __float_as_uint(a);
    unsigned rh = x + 0x7FFFu + ((x >> 16) & 1u);
    unsigned short hs = (unsigned short)(rh >> 16);
    float fh = __uint_as_float((unsigned)hs << 16);
    float r  = a - fh;                    // exact (Sterbenz-range)
    unsigned y  = __float_as_uint(r);
    unsigned rl = y + 0x7FFFu + ((y >> 16) & 1u);
    h = hs;
    l = (unsigned short)(rl >> 16);
}

// ---------------------------------------------------------------------------
// weight repack: W[k][n] f32 -> Wt_hi[n][k], Wt_lo[n][k] bf16 planes
// TRANS=false: src already [n][k]
// ---------------------------------------------------------------------------
template<bool TRANS>
__global__ __launch_bounds__(256)
void repack_kernel(const float* __restrict__ src, int N, int kbits,
                   unsigned short* __restrict__ hi, unsigned short* __restrict__ lo)
{
    int idx = blockIdx.x * 256 + threadIdx.x;
    int K = 1 << kbits;
    int k = idx & (K - 1);
    int n = idx >> kbits;
    float v = TRANS ? src[(size_t)k * N + n] : src[idx];
    unsigned short h, l;
    split_bf16(v, h, l);
    hi[idx] = h; lo[idx] = l;
}

// ---------------------------------------------------------------------------
// Split-bf16 MFMA GEMM: C[M][NDIM] = act(A[M][KDIM] @ W + bias)
// A: f32, converted to (hi,lo) bf16 during LDS staging.
// W: pre-split bf16 planes in [N][K] layout (k-contiguous rows).
// 3-product emulation: Ah*Wh + Ah*Wl + Al*Wh  (err ~1e-6 on this data).
// 128x128 tile, BK=32, 256 threads = 4 waves (2x2), wave tile 64x64,
// 16x16x32 bf16 MFMA, LDS pad 40 shorts (80B stride -> ~2-way banks).
// PROJ: gather A rows from moves via idxf; fused ar_out epilogue.
// ---------------------------------------------------------------------------
#define LDSPAD 40

template<int KDIM, int NDIM, bool RELU, bool PROJ>
__global__ __launch_bounds__(256, 2)
void gemm_bf16s(const float* __restrict__ A,
                const unsigned short* __restrict__ Wh,
                const unsigned short* __restrict__ Wl,
                const float* __restrict__ bias,
                float* __restrict__ C,
                const float* __restrict__ idxf,
                const float* __restrict__ moves,
                const float* __restrict__ xres,
                const int*   __restrict__ atype,
                float* __restrict__ out_ar)
{
    __shared__ unsigned short AhS[128 * LDSPAD];
    __shared__ unsigned short AlS[128 * LDSPAD];
    __shared__ unsigned short WhS[128 * LDSPAD];
    __shared__ unsigned short WlS[128 * LDSPAD];

    const int tid  = threadIdx.x;
    const int lane = tid & 63;
    const int wid  = tid >> 6;
    const int wr   = wid >> 1;
    const int wc   = wid & 1;
    const int row0 = blockIdx.x * 128;
    const int col0 = blockIdx.y * 128;

    // ---- staging coordinates ----
    const int sr = tid >> 1;           // A stage row 0..127
    const int sc = (tid & 1) * 16;     // A stage k offset within chunk
    const float* arow;
    if constexpr (PROJ) {
        const int slot = row0 + sr;
        const int mi = (int)idxf[slot];
        arow = moves + ((size_t)slot * 4 + mi) * KDIM;
    } else {
        arow = A + (size_t)(row0 + sr) * KDIM;
    }
    const int wn = tid & 127;
    const unsigned short* wrow = ((tid >> 7) ? Wl : Wh) + (size_t)(col0 + wn) * KDIM;
    unsigned short* wdst = (tid >> 7) ? WlS : WhS;

    // ---- fragment LDS offsets (ushort units) ----
    const int fr   = lane & 15;
    const int fkg  = (lane >> 4) * 8;
    const int aoff = (wr * 64 + fr) * LDSPAD + fkg;
    const int woff = (wc * 64 + fr) * LDSPAD + fkg;

    f32x4 acc[4][4];
#pragma unroll
    for (int i = 0; i < 4; i++)
#pragma unroll
        for (int j = 0; j < 4; j++) acc[i][j] = {0.f, 0.f, 0.f, 0.f};

    // preload chunk 0
    float4 pa[4];
    uint4  pw[4];
#pragma unroll
    for (int i = 0; i < 4; i++) pa[i] = *(const float4*)&arow[sc + i * 4];
#pragma unroll
    for (int i = 0; i < 4; i++) pw[i] = *(const uint4*)&wrow[i * 8];

    for (int k0 = 0; k0 < KDIM; k0 += 32) {
        // ---- convert + write staged regs to LDS ----
        {
            unsigned hw[8], lw[8];
#pragma unroll
            for (int i = 0; i < 4; i++) {
                unsigned short h0, l0, h1, l1;
                split_bf16(pa[i].x, h0, l0);
                split_bf16(pa[i].y, h1, l1);
                hw[i * 2 + 0] = (unsigned)h0 | ((unsigned)h1 << 16);
                lw[i * 2 + 0] = (unsigned)l0 | ((unsigned)l1 << 16);
                split_bf16(pa[i].z, h0, l0);
                split_bf16(pa[i].w, h1, l1);
                hw[i * 2 + 1] = (unsigned)h0 | ((unsigned)h1 << 16);
                lw[i * 2 + 1] = (unsigned)l0 | ((unsigned)l1 << 16);
            }
            *(uint4*)&AhS[sr * LDSPAD + sc]     = (uint4){hw[0], hw[1], hw[2], hw[3]};
            *(uint4*)&AhS[sr * LDSPAD + sc + 8] = (uint4){hw[4], hw[5], hw[6], hw[7]};
            *(uint4*)&AlS[sr * LDSPAD + sc]     = (uint4){lw[0], lw[1], lw[2], lw[3]};
            *(uint4*)&AlS[sr * LDSPAD + sc + 8] = (uint4){lw[4], lw[5], lw[6], lw[7]};
#pragma unroll
            for (int i = 0; i < 4; i++)
                *(uint4*)&wdst[wn * LDSPAD + i * 8] = pw[i];
        }
        __syncthreads();

        // ---- preload next chunk (hides HBM latency under MFMA) ----
        if (k0 + 32 < KDIM) {
#pragma unroll
            for (int i = 0; i < 4; i++) pa[i] = *(const float4*)&arow[k0 + 32 + sc + i * 4];
#pragma unroll
            for (int i = 0; i < 4; i++) pw[i] = *(const uint4*)&wrow[k0 + 32 + i * 8];
        }

        // ---- fragments + MFMA ----
        bf16x8 ah[4], al[4], wh[4], wl[4];
#pragma unroll
        for (int i = 0; i < 4; i++) {
            ah[i] = *(const bf16x8*)&AhS[aoff + i * 16 * LDSPAD];
            al[i] = *(const bf16x8*)&AlS[aoff + i * 16 * LDSPAD];
        }
#pragma unroll
        for (int j = 0; j < 4; j++) {
            wh[j] = *(const bf16x8*)&WhS[woff + j * 16 * LDSPAD];
            wl[j] = *(const bf16x8*)&WlS[woff + j * 16 * LDSPAD];
        }
#pragma unroll
        for (int i = 0; i < 4; i++)
#pragma unroll
            for (int j = 0; j < 4; j++) {
                acc[i][j] = __builtin_amdgcn_mfma_f32_16x16x32_bf16(ah[i], wh[j], acc[i][j], 0, 0, 0);
                acc[i][j] = __builtin_amdgcn_mfma_f32_16x16x32_bf16(ah[i], wl[j], acc[i][j], 0, 0, 0);
                acc[i][j] = __builtin_amdgcn_mfma_f32_16x16x32_bf16(al[i], wh[j], acc[i][j], 0, 0, 0);
            }
        __syncthreads();
    }

    // ---- epilogue: C/D layout col = lane&15, row = (lane>>4)*4 + reg ----
#pragma unroll
    for (int j = 0; j < 4; j++) {
        const int col = col0 + wc * 64 + j * 16 + fr;
        const float bv = bias ? bias[col] : 0.f;
#pragma unroll
        for (int i = 0; i < 4; i++) {
            const int rbase = row0 + wr * 64 + i * 16 + (lane >> 4) * 4;
#pragma unroll
            for (int r = 0; r < 4; r++) {
                float v = acc[i][j][r] + bv;
                if constexpr (RELU) v = fmaxf(v, 0.f);
                const size_t off = (size_t)(rbase + r) * NDIM + col;
                C[off] = v;
                if constexpr (PROJ) {
                    float xv = xres[off];
                    out_ar[off] = (atype[rbase + r] == 0) ? xv + v : xv;
                }
            }
        }
    }
}

// ---------------------------------------------------------------------------
// JAX threefry2x32 with key (0, 42)
// ---------------------------------------------------------------------------
__device__ __forceinline__ void threefry2x32_k42(unsigned int& x0, unsigned int& x1)
{
    const unsigned int ks0 = 0u;
    const unsigned int ks1 = 42u;
    const unsigned int ks2 = 0x1BD11BDAu ^ 42u;
    x0 += ks0; x1 += ks1;
#define TFR(r) { x0 += x1; x1 = (x1 << (r)) | (x1 >> (32 - (r))); x1 ^= x0; }
    TFR(13) TFR(15) TFR(26) TFR(6)
    x0 += ks1; x1 += ks2 + 1u;
    TFR(17) TFR(29) TFR(16) TFR(24)
    x0 += ks2; x1 += ks0 + 2u;
    TFR(13) TFR(15) TFR(26) TFR(6)
    x0 += ks0; x1 += ks1 + 3u;
    TFR(17) TFR(29) TFR(16) TFR(24)
    x0 += ks1; x1 += ks2 + 4u;
    TFR(13) TFR(15) TFR(26) TFR(6)
    x0 += ks2; x1 += ks0 + 5u;
#undef TFR
}

// ---------------------------------------------------------------------------
// logits via algebraic rewrite: logit[s,m] = u[s].Hk[s,m] + q[s].bk2
// (u = Wk2 @ q). Softmax + gumbel-argmax, plus top-2 gap for cleanup.
// ---------------------------------------------------------------------------
__global__ __launch_bounds__(256)
void logits_kernel(const float* __restrict__ u, const float* __restrict__ Hk,
                   const float* __restrict__ q, const float* __restrict__ bk2,
                   const int* __restrict__ mask,
                   float* __restrict__ out_logits, float* __restrict__ out_policy,
                   float* __restrict__ out_index, float* __restrict__ gaps,
                   int t0)
{
    const int tl   = blockIdx.x * 256 + threadIdx.x;   // quarter-local move row
    const int t    = t0 + tl;                          // global move row
    const int slot = t >> 2;
    const int m    = t & 3;

    const float4* up = (const float4*)&u[(size_t)slot * F2_];
    const float4* hp = (const float4*)&Hk[(size_t)tl * F2_];
    double dot = 0.0;
#pragma unroll
    for (int i = 0; i < 64; i++) {
        float4 a = up[i], b = hp[i];
        dot += (double)a.x * b.x; dot += (double)a.y * b.y;
        dot += (double)a.z * b.z; dot += (double)a.w * b.w;
    }
    {
        const float4* qp = (const float4*)&q[(size_t)slot * F4_];
        const float4* bp = (const float4*)bk2;
        double qb = 0.0;
#pragma unroll
        for (int i = 0; i < 32; i++) {
            float4 a = qp[i], b = bp[i];
            qb += (double)a.x * b.x; qb += (double)a.y * b.y;
            qb += (double)a.z * b.z; qb += (double)a.w * b.w;
        }
        dot += qb;
    }

    const bool legal = (mask[t] != 0);

    double lmin = fmin(dot, __shfl_xor(dot, 1));
    lmin = fmin(lmin, __shfl_xor(lmin, 2));
    const double lm = legal ? dot : lmin;
    double lmax = fmax(lm, __shfl_xor(lm, 1));
    lmax = fmax(lmax, __shfl_xor(lmax, 2));
    const double e = legal ? exp(lm - lmax) : 0.0;
    double esum = e + __shfl_xor(e, 1);
    esum += __shfl_xor(esum, 2);
    const double policy = e / esum;

    out_logits[t] = (float)dot;
    out_policy[t] = (float)policy;

    const double sl = (policy > 0.0) ? log(policy) : -1e30;

    unsigned int x0 = 0u;
    unsigned int x1 = (unsigned int)t;
    threefry2x32_k42(x0, x1);
    const unsigned int bits = x0 ^ x1;

    const float f  = __uint_as_float(0x3f800000u | (bits >> 9)) - 1.0f;
    const float uf = fmaxf(1.17549435e-38f, f);
    const double g = -log(-log((double)uf));
    const double v = sl + g;

    // argmax over 4 lanes, lowest index wins ties
    int    best = m;
    double bv   = v;
    {
        double ov = __shfl_xor(bv, 1); int oi = __shfl_xor(best, 1);
        if (ov > bv || (ov == bv && oi < best)) { bv = ov; best = oi; }
        ov = __shfl_xor(bv, 2); oi = __shfl_xor(best, 2);
        if (ov > bv || (ov == bv && oi < best)) { bv = ov; best = oi; }
    }

    // top-2 gap of gumbel scores (for near-tie cleanup)
    double a1 = fmax(v, __shfl_xor(v, 1));
    double b1 = fmin(v, __shfl_xor(v, 1));
    double a2 = __shfl_xor(a1, 2);
    double b2 = __shfl_xor(b1, 2);
    double top2 = (a1 >= a2) ? fmax(a2, b1) : fmax(a1, b2);
    double top1 = fmax(a1, a2);

    if (m == 0) {
        out_index[slot] = (float)best;
        gaps[slot] = (float)(top1 - top2);
    }
}

// ---------------------------------------------------------------------------
// cleanup: exact f64 recompute of near-tie slots (gap < TAU), fixes index.
// ---------------------------------------------------------------------------
#define TAU_ 3e-3f

__global__ __launch_bounds__(256)
void cleanup_kernel(const float* __restrict__ x, const float* __restrict__ moves,
                    const int* __restrict__ mask,
                    const float* __restrict__ Wq1, const float* __restrict__ bq1,
                    const float* __restrict__ Wq2, const float* __restrict__ bq2,
                    const float* __restrict__ Wk1, const float* __restrict__ bk1,
                    const float* __restrict__ Wk2, const float* __restrict__ bk2,
                    const float* __restrict__ gaps, float* __restrict__ out_index)
{
    __shared__ double h1[256];
    __shared__ double qv[128];
    __shared__ double kv[128];
    __shared__ double red[256];
    __shared__ double dotS[4];

    const int j = threadIdx.x;
    for (int s = blockIdx.x; s < R_; s += gridDim.x) {
        if (gaps[s] >= TAU_) continue;     // uniform per block

        {   // h1 = relu(x[s] @ Wq1 + bq1)
            const float* xr = x + (size_t)s * F_;
            double acc = 0.0;
            for (int c = 0; c < F_; c++) acc += (double)xr[c] * (double)Wq1[(size_t)c * F2_ + j];
            h1[j] = fmax(acc + (double)bq1[j], 0.0);
        }
        __syncthreads();
        if (j < F4_) {   // q = h1 @ Wq2 + bq2
            double acc = 0.0;
            for (int c = 0; c < F2_; c++) acc += h1[c] * (double)Wq2[(size_t)c * F4_ + j];
            qv[j] = acc + (double)bq2[j];
        }
        __syncthreads();

        for (int mv = 0; mv < 4; mv++) {
            const float* mr = moves + ((size_t)s * 4 + mv) * F2_;
            double acc = 0.0;
            for (int c = 0; c < F2_; c++) acc += (double)mr[c] * (double)Wk1[(size_t)c * F2_ + j];
            __syncthreads();
            h1[j] = fmax(acc + (double)bk1[j], 0.0);
            __syncthreads();
            if (j < F4_) {
                double a2 = 0.0;
                for (int c = 0; c < F2_; c++) a2 += h1[c] * (double)Wk2[(size_t)c * F4_ + j];
                kv[j] = a2 + (double)bk2[j];
            }
            __syncthreads();
            red[j] = (j < F4_) ? qv[j] * kv[j] : 0.0;
            __syncthreads();
            for (int st = 128; st > 0; st >>= 1) {
                if (j < st) red[j] += red[j + st];
                __syncthreads();
            }
            if (j == 0) dotS[mv] = red[0];
            __syncthreads();
        }

        if (j == 0) {
            double lmin = dotS[0];
#pragma unroll
            for (int mv = 1; mv < 4; mv++) lmin = fmin(lmin, dotS[mv]);
            double lm[4]; bool lg[4];
            double lmax = -1e300;
#pragma unroll
            for (int mv = 0; mv < 4; mv++) {
                lg[mv] = (mask[(size_t)s * 4 + mv] != 0);
                lm[mv] = lg[mv] ? dotS[mv] : lmin;
                lmax = fmax(lmax, lm[mv]);
            }
            double e[4]; double esum = 0.0;
#pragma unroll
            for (int mv = 0; mv < 4; mv++) {
                e[mv] = lg[mv] ? exp(lm[mv] - lmax) : 0.0;
                esum += e[mv];
            }
            int best = -1; double bv = -1e308;
#pragma unroll
            for (int mv = 0; mv < 4; mv++) {
                double pol = e[mv] / esum;
                double sl = (pol > 0.0) ? log(pol) : -1e30;
                unsigned x0 = 0u, x1 = (unsigned)(s * 4 + mv);
                threefry2x32_k42(x0, x1);
                unsigned bits = x0 ^ x1;
                float fu = __uint_as_float(0x3f800000u | (bits >> 9)) - 1.0f;
                float uf = fmaxf(1.17549435e-38f, fu);
                double g = -log(-log((double)uf));
                double v = sl + g;
                if (v > bv) { bv = v; best = mv; }
            }
            out_index[s] = (float)best;
        }
        __syncthreads();
    }
}

// ===========================================================================
// LEGACY FALLBACK (previous verified kernels) — used if d_ws is too small
// ===========================================================================
template<int KDIM>
__global__ __launch_bounds__(256, 3)
void mlp2_kernel(const float* __restrict__ A,
                 const float* __restrict__ W1, const float* __restrict__ b1,
                 const float* __restrict__ W2, const float* __restrict__ b2,
                 float* __restrict__ out)
{
    __shared__ float H[32][260];
    __shared__ float As[32][20];
    __shared__ float Bs[4096];

    const int tid  = threadIdx.x;
    const int row0 = blockIdx.x * 32;
    const int tx   = tid & 31;
    const int ty   = tid >> 5;

    float acc[4][8];
#pragma unroll
    for (int i = 0; i < 4; i++)
#pragma unroll
        for (int j = 0; j < 8; j++) acc[i][j] = 0.f;

    for (int k0 = 0; k0 < KDIM; k0 += 16) {
        {
            int r = tid >> 3;
            int c = (tid & 7) * 2;
            float2 v = *(const float2*)&A[(size_t)(row0 + r) * KDIM + k0 + c];
            *(float2*)&As[r][c] = v;
        }
        {
            int kk = tid >> 4;
            int c0 = (tid & 15) * 16;
            const float* src = &W1[(size_t)(k0 + kk) * F2_ + c0];
            float* dst = &Bs[kk * F2_ + c0];
#pragma unroll
            for (int j = 0; j < 4; j++) ((float4*)dst)[j] = ((const float4*)src)[j];
        }
        __syncthreads();
#pragma unroll
        for (int kk = 0; kk < 16; kk += 4) {
            float4 a[4];
#pragma unroll
            for (int i = 0; i < 4; i++) a[i] = *(const float4*)&As[ty * 4 + i][kk];
#pragma unroll
            for (int u = 0; u < 4; u++) {
                float4 w0 = *(const float4*)&Bs[(kk + u) * F2_ + tx * 8];
                float4 w1 = *(const float4*)&Bs[(kk + u) * F2_ + tx * 8 + 4];
#pragma unroll
                for (int i = 0; i < 4; i++) {
                    float av = ((const float*)&a[i])[u];
                    acc[i][0] += av * w0.x; acc[i][1] += av * w0.y;
                    acc[i][2] += av * w0.z; acc[i][3] += av * w0.w;
                    acc[i][4] += av * w1.x; acc[i][5] += av * w1.y;
                    acc[i][6] += av * w1.z; acc[i][7] += av * w1.w;
                }
            }
        }
        __syncthreads();
    }
    {
        float4 b1a = *(const float4*)&b1[tx * 8];
        float4 b1b = *(const float4*)&b1[tx * 8 + 4];
        const float bv[8] = {b1a.x, b1a.y, b1a.z, b1a.w, b1b.x, b1b.y, b1b.z, b1b.w};
#pragma unroll
        for (int i = 0; i < 4; i++) {
            float4 h0, h1;
            h0.x = fmaxf(acc[i][0] + bv[0], 0.f);
            h0.y = fmaxf(acc[i][1] + bv[1], 0.f);
            h0.z = fmaxf(acc[i][2] + bv[2], 0.f);
            h0.w = fmaxf(acc[i][3] + bv[3], 0.f);
            h1.x = fmaxf(acc[i][4] + bv[4], 0.f);
            h1.y = fmaxf(acc[i][5] + bv[5], 0.f);
            h1.z = fmaxf(acc[i][6] + bv[6], 0.f);
            h1.w = fmaxf(acc[i][7] + bv[7], 0.f);
            *(float4*)&H[ty * 4 + i][tx * 8]     = h0;
            *(float4*)&H[ty * 4 + i][tx * 8 + 4] = h1;
        }
    }
    __syncthreads();

    float acc2[4][4];
#pragma unroll
    for (int i = 0; i < 4; i++)
#pragma unroll
        for (int j = 0; j < 4; j++) acc2[i][j] = 0.f;

    for (int k0 = 0; k0 < F2_; k0 += 32) {
        {
            int kk = tid >> 3;
            int c0 = (tid & 7) * 16;
            const float* src = &W2[(size_t)(k0 + kk) * F4_ + c0];
            float* dst = &Bs[kk * F4_ + c0];
#pragma unroll
            for (int j = 0; j < 4; j++) ((float4*)dst)[j] = ((const float4*)src)[j];
        }
        __syncthreads();
#pragma unroll
        for (int kk = 0; kk < 32; kk += 4) {
            float4 h[4];
#pragma unroll
            for (int i = 0; i < 4; i++) h[i] = *(const float4*)&H[ty * 4 + i][k0 + kk];
#pragma unroll
            for (int u = 0; u < 4; u++) {
                float4 w = *(const float4*)&Bs[(kk + u) * F4_ + tx * 4];
#pragma unroll
                for (int i = 0; i < 4; i++) {
                    float hv = ((const float*)&h[i])[u];
                    acc2[i][0] += hv * w.x; acc2[i][1] += hv * w.y;
                    acc2[i][2] += hv * w.z; acc2[i][3] += hv * w.w;
                }
            }
        }
        __syncthreads();
    }
    {
        float4 bb = *(const float4*)&b2[tx * 4];
#pragma unroll
        for (int i = 0; i < 4; i++) {
            float4 o;
            o.x = acc2[i][0] + bb.x;
            o.y = acc2[i][1] + bb.y;
            o.z = acc2[i][2] + bb.z;
            o.w = acc2[i][3] + bb.w;
            *(float4*)&out[(size_t)(row0 + ty * 4 + i) * F4_ + tx * 4] = o;
        }
    }
}

__global__ __launch_bounds__(256)
void logits_sample_kernel(const float* __restrict__ Q, const float* __restrict__ Kv,
                          const int* __restrict__ mask,
                          float* __restrict__ out_logits, float* __restrict__ out_policy,
                          float* __restrict__ out_index)
{
    const int t    = blockIdx.x * 256 + threadIdx.x;
    const int slot = t >> 2;
    const int m    = t & 3;

    const float4* qp = (const float4*)&Q[(size_t)slot * F4_];
    const float4* kp = (const float4*)&Kv[(size_t)t * F4_];
    double dot = 0.0;
#pragma unroll
    for (int i = 0; i < 32; i++) {
        float4 a = qp[i], b = kp[i];
        dot += (double)a.x * b.x; dot += (double)a.y * b.y;
        dot += (double)a.z * b.z; dot += (double)a.w * b.w;
    }

    const bool legal = (mask[t] != 0);

    double lmin = fmin(dot, __shfl_xor(dot, 1));
    lmin = fmin(lmin, __shfl_xor(lmin, 2));
    const double lm = legal ? dot : lmin;
    double lmax = fmax(lm, __shfl_xor(lm, 1));
    lmax = fmax(lmax, __shfl_xor(lmax, 2));
    const double e = legal ? exp(lm - lmax) : 0.0;
    double esum = e + __shfl_xor(e, 1);
    esum += __shfl_xor(esum, 2);
    const double policy = e / esum;

    out_logits[t] = (float)dot;
    out_policy[t] = (float)policy;

    const double sl = (policy > 0.0) ? log(policy) : -1e30;

    unsigned int x0 = 0u;
    unsigned int x1 = (unsigned int)t;
    threefry2x32_k42(x0, x1);
    const unsigned int bits = x0 ^ x1;

    const float f  = __uint_as_float(0x3f800000u | (bits >> 9)) - 1.0f;
    const float uf = fmaxf(1.17549435e-38f, f);
    const double g = -log(-log((double)uf));
    const double v = sl + g;

    int    best = m;
    double bv   = v;
    {
        double ov = __shfl_xor(bv, 1); int oi = __shfl_xor(best, 1);
        if (ov > bv || (ov == bv && oi < best)) { bv = ov; best = oi; }
        ov = __shfl_xor(bv, 2); oi = __shfl_xor(best, 2);
        if (ov > bv || (ov == bv && oi < best)) { bv = ov; best = oi; }
    }
    if (m == 0) out_index[slot] = (float)best;
}

__global__ __launch_bounds__(256, 3)
void proj_kernel(const float* __restrict__ moves, const float* __restrict__ idxf,
                 const float* __restrict__ Wp, const float* __restrict__ bp,
                 const float* __restrict__ x, const int* __restrict__ atype,
                 float* __restrict__ out_ar, float* __restrict__ out_proj)
{
    __shared__ float As[32][260];
    __shared__ float Bs[32 * 128];

    const int tid  = threadIdx.x;
    const int row0 = blockIdx.x * 32;
    const int col0 = blockIdx.y * 128;
    const int tx   = tid & 31;
    const int ty   = tid >> 5;

#pragma unroll
    for (int it = 0; it < 8; it++) {
        int r = (tid >> 6) + it * 4;
        int c = (tid & 63) * 4;
        int slot = row0 + r;
        int mi = (int)idxf[slot];
        float4 v = *(const float4*)&moves[((size_t)slot * 4 + mi) * F2_ + c];
        *(float4*)&As[r][c] = v;
    }
    __syncthreads();

    float acc[4][4];
#pragma unroll
    for (int i = 0; i < 4; i++)
#pragma unroll
        for (int j = 0; j < 4; j++) acc[i][j] = 0.f;

    for (int k0 = 0; k0 < F2_; k0 += 32) {
        {
            int kk = tid >> 3;
            int c0 = (tid & 7) * 16;
            const float* src = &Wp[(size_t)(k0 + kk) * F_ + col0 + c0];
            float* dst = &Bs[kk * 128 + c0];
#pragma unroll
            for (int j = 0; j < 4; j++) ((float4*)dst)[j] = ((const float4*)src)[j];
        }
        __syncthreads();
#pragma unroll
        for (int kk = 0; kk < 32; kk += 4) {
            float4 h[4];
#pragma unroll
            for (int i = 0; i < 4; i++) h[i] = *(const float4*)&As[ty * 4 + i][k0 + kk];
#pragma unroll
            for (int u = 0; u < 4; u++) {
                float4 w = *(const float4*)&Bs[(kk + u) * 128 + tx * 4];
#pragma unroll
                for (int i = 0; i < 4; i++) {
                    float hv = ((const float*)&h[i])[u];
                    acc[i][0] += hv * w.x; acc[i][1] += hv * w.y;
                    acc[i][2] += hv * w.z; acc[i][3] += hv * w.w;
                }
            }
        }
        __syncthreads();
    }

    float4 bb = *(const float4*)&bp[col0 + tx * 4];
#pragma unroll
    for (int i = 0; i < 4; i++) {
        int row = row0 + ty * 4 + i;
        float4 p;
        p.x = acc[i][0] + bb.x;
        p.y = acc[i][1] + bb.y;
        p.z = acc[i][2] + bb.z;
        p.w = acc[i][3] + bb.w;
        size_t off = (size_t)row * F_ + col0 + tx * 4;
        *(float4*)&out_proj[off] = p;
        float4 a = *(const float4*)&x[off];
        bool valid = (atype[row] == 0);
        float4 r4;
        r4.x = valid ? a.x + p.x : a.x;
        r4.y = valid ? a.y + p.y : a.y;
        r4.z = valid ? a.z + p.z : a.z;
        r4.w = valid ? a.w + p.w : a.w;
        *(float4*)&out_ar[off] = r4;
    }
}

// ---------------------------------------------------------------------------
extern "C" void kernel_launch(void* const* d_in, const int* in_sizes, int n_in,
                              void* d_out, int out_size, void* d_ws, size_t ws_size,
                              hipStream_t stream)
{
    (void)in_sizes; (void)n_in; (void)out_size;

    const int*   atype = (const int*)d_in[0];
    const float* x     = (const float*)d_in[1];
    const float* moves = (const float*)d_in[2];
    const int*   mask  = (const int*)d_in[3];
    const float* Wq1   = (const float*)d_in[4];
    const float* bq1   = (const float*)d_in[5];
    const float* Wq2   = (const float*)d_in[6];
    const float* bq2   = (const float*)d_in[7];
    const float* Wk1   = (const float*)d_in[8];
    const float* bk1   = (const float*)d_in[9];
    const float* Wk2   = (const float*)d_in[10];
    const float* bk2   = (const float*)d_in[11];
    const float* Wp    = (const float*)d_in[12];
    const float* bp    = (const float*)d_in[13];

    float* out_logits = (float*)d_out;                   // [R_,4]
    float* out_policy = out_logits + RM_;                // [R_,4]
    float* out_index  = out_policy + RM_;                // [R_,1]
    float* out_ar     = out_index + R_;                  // [R_,512]
    float* out_proj   = out_ar + (size_t)R_ * F_;        // [R_,512]

    // Workspace: split-bf16 weight planes (1.5 MB) + gaps (128 KB)
    const size_t WS_NEED = (size_t)786432 * 2 + (size_t)R_ * 4;   // 1,703,936 B

    if (d_ws != nullptr && ws_size >= WS_NEED) {
        unsigned short* wq1h = (unsigned short*)d_ws;    // [256][512]
        unsigned short* wq1l = wq1h + 131072;
        unsigned short* wq2h = wq1l + 131072;            // [128][256]
        unsigned short* wq2l = wq2h + 32768;
        unsigned short* wk1h = wq2l + 32768;             // [256][256]
        unsigned short* wk1l = wk1h + 65536;
        unsigned short* wk2h = wk1l + 65536;             // [256][128] (= Wk2 natural, W for u-GEMM)
        unsigned short* wk2l = wk2h + 32768;
        unsigned short* wph  = wk2l + 32768;             // [512][256]
        unsigned short* wpl  = wph + 131072;
        float* gaps = (float*)(wpl + 131072);

        // scratch carved out of d_out regions that proj overwrites last:
        float* Hq = out_ar;                 // [32768][256]  (32 MB)
        float* qv = out_ar + 8388608;       // [32768][128]  (16 MB)
        float* uv = out_proj;               // [32768][256]  (32 MB)
        float* Hk = out_ar;                 // quarter scratch [32768][256] (reuses Hq region)

        // ---- repack weights to [N][K] bf16 hi/lo planes ----
        repack_kernel<true ><<<512, 256, 0, stream>>>(Wq1, F2_, 9, wq1h, wq1l);
        repack_kernel<true ><<<128, 256, 0, stream>>>(Wq2, F4_, 8, wq2h, wq2l);
        repack_kernel<true ><<<256, 256, 0, stream>>>(Wk1, F2_, 8, wk1h, wk1l);
        repack_kernel<false><<<128, 256, 0, stream>>>(Wk2, F4_, 7, wk2h, wk2l);
        repack_kernel<true ><<<512, 256, 0, stream>>>(Wp,  F_,  8, wph,  wpl);

        // ---- Q path ----
        dim3 g1(R_ / 128, 2);
        gemm_bf16s<512, 256, true,  false><<<g1, 256, 0, stream>>>(
            x, wq1h, wq1l, bq1, Hq, nullptr, nullptr, nullptr, nullptr, nullptr);
        dim3 g2(R_ / 128, 1);
        gemm_bf16s<256, 128, false, false><<<g2, 256, 0, stream>>>(
            Hq, wq2h, wq2l, bq2, qv, nullptr, nullptr, nullptr, nullptr, nullptr);
        dim3 g3(R_ / 128, 2);
        gemm_bf16s<128, 256, false, false><<<g3, 256, 0, stream>>>(
            qv, wk2h, wk2l, nullptr, uv, nullptr, nullptr, nullptr, nullptr, nullptr);

        // ---- K path in 4 quarters (Hk scratch = 32 MB) + logits ----
        for (int qi = 0; qi < 4; qi++) {
            const float* mseg = moves + (size_t)qi * 32768 * F2_;
            gemm_bf16s<256, 256, true, false><<<g3, 256, 0, stream>>>(
                mseg, wk1h, wk1l, bk1, Hk, nullptr, nullptr, nullptr, nullptr, nullptr);
            logits_kernel<<<128, 256, 0, stream>>>(
                uv, Hk, qv, bk2, mask, out_logits, out_policy, out_index, gaps, qi * 32768);
        }

        // ---- near-tie exact recompute ----
        cleanup_kernel<<<2048, 256, 0, stream>>>(
            x, moves, mask, Wq1, bq1, Wq2, bq2, Wk1, bk1, Wk2, bk2, gaps, out_index);

        // ---- gather + projection + ar_out epilogue ----
        dim3 gp(R_ / 128, 4);
        gemm_bf16s<256, 512, false, true><<<gp, 256, 0, stream>>>(
            nullptr, wph, wpl, bp, out_proj, out_index, moves, x, atype, out_ar);
    } else {
        // -------- legacy fp32 path (previous verified kernel) --------
        float* Q  = out_proj;
        float* Kv = out_ar;

        mlp2_kernel<F_><<<R_ / 32, 256, 0, stream>>>(x, Wq1, bq1, Wq2, bq2, Q);
        mlp2_kernel<F2_><<<RM_ / 32, 256, 0, stream>>>(moves, Wk1, bk1, Wk2, bk2, Kv);
        logits_sample_kernel<<<RM_ / 256, 256, 0, stream>>>(Q, Kv, mask,
                                                            out_logits, out_policy, out_index);
        dim3 pgrid(R_ / 32, 4);
        proj_kernel<<<pgrid, 256, 0, stream>>>(moves, out_index, Wp, bp, x, atype,
                                               out_ar, out_proj);
    }
}

// Round 2
// 822.446 us; speedup vs baseline: 1.2768x; 1.0658x over previous
//
#include <hip/hip_runtime.h>

// Problem constants
#define B_   64
#define T_   512
#define F_   512
#define F2_  256
#define F4_  128
#define R_   32768      // B*T slots
#define RM_  131072     // R*4 move rows

typedef __attribute__((ext_vector_type(8))) short bf16x8;
typedef __attribute__((ext_vector_type(4))) float f32x4;

// ---------------------------------------------------------------------------
// split fp32 -> (hi, lo) bf16 with RNE; a ~= hi + lo to ~16-17 mantissa bits
// ---------------------------------------------------------------------------
__device__ __forceinline__ void split_bf16(float a, unsigned short& h, unsigned short& l)
{
    unsigned x  = __float_as_uint(a);
    unsigned rh = x + 0x7FFFu + ((x >> 16) & 1u);
    unsigned short hs = (unsigned short)(rh >> 16);
    float fh = __uint_as_float((unsigned)hs << 16);
    float r  = a - fh;                    // exact (Sterbenz-range)
    unsigned y  = __float_as_uint(r);
    unsigned rl = y + 0x7FFFu + ((y >> 16) & 1u);
    h = hs;
    l = (unsigned short)(rl >> 16);
}

// ---------------------------------------------------------------------------
// weight repack: W[k][n] f32 -> Wt_hi[n][k], Wt_lo[n][k] bf16 planes
// TRANS=false: src already [n][k]
// ---------------------------------------------------------------------------
template<bool TRANS>
__global__ __launch_bounds__(256)
void repack_kernel(const float* __restrict__ src, int N, int kbits,
                   unsigned short* __restrict__ hi, unsigned short* __restrict__ lo)
{
    int idx = blockIdx.x * 256 + threadIdx.x;
    int K = 1 << kbits;
    int k = idx & (K - 1);
    int n = idx >> kbits;
    float v = TRANS ? src[(size_t)k * N + n] : src[idx];
    unsigned short h, l;
    split_bf16(v, h, l);
    hi[idx] = h; lo[idx] = l;
}

// ---------------------------------------------------------------------------
// Split-bf16 MFMA GEMM: C[M][NDIM] = act(A[M][KDIM] @ W + bias)
// A: f32, converted to (hi,lo) bf16 during LDS staging.
// W: pre-split bf16 planes in [N][K] layout (k-contiguous rows).
// 3-product emulation: Ah*Wh + Ah*Wl + Al*Wh  (err ~1e-6 on this data).
// 128x128 tile, BK=32, 256 threads = 4 waves (2x2), wave tile 64x64,
// 16x16x32 bf16 MFMA, LDS pad 40 shorts (80B stride -> ~2-way banks).
// PROJ: gather A rows from moves via idxf; fused ar_out epilogue.
// ---------------------------------------------------------------------------
#define LDSPAD 40

template<int KDIM, int NDIM, bool RELU, bool PROJ>
__global__ __launch_bounds__(256, 2)
void gemm_bf16s(const float* __restrict__ A,
                const unsigned short* __restrict__ Wh,
                const unsigned short* __restrict__ Wl,
                const float* __restrict__ bias,
                float* __restrict__ C,
                const float* __restrict__ idxf,
                const float* __restrict__ moves,
                const float* __restrict__ xres,
                const int*   __restrict__ atype,
                float* __restrict__ out_ar)
{
    __shared__ unsigned short AhS[128 * LDSPAD];
    __shared__ unsigned short AlS[128 * LDSPAD];
    __shared__ unsigned short WhS[128 * LDSPAD];
    __shared__ unsigned short WlS[128 * LDSPAD];

    const int tid  = threadIdx.x;
    const int lane = tid & 63;
    const int wid  = tid >> 6;
    const int wr   = wid >> 1;
    const int wc   = wid & 1;
    const int row0 = blockIdx.x * 128;
    const int col0 = blockIdx.y * 128;

    // ---- staging coordinates ----
    const int sr = tid >> 1;           // A stage row 0..127
    const int sc = (tid & 1) * 16;     // A stage k offset within chunk
    const float* arow;
    if constexpr (PROJ) {
        const int slot = row0 + sr;
        const int mi = (int)idxf[slot];
        arow = moves + ((size_t)slot * 4 + mi) * KDIM;
    } else {
        arow = A + (size_t)(row0 + sr) * KDIM;
    }
    const int wn = tid & 127;
    const unsigned short* wrow = ((tid >> 7) ? Wl : Wh) + (size_t)(col0 + wn) * KDIM;
    unsigned short* wdst = (tid >> 7) ? WlS : WhS;

    // ---- fragment LDS offsets (ushort units) ----
    const int fr   = lane & 15;
    const int fkg  = (lane >> 4) * 8;
    const int aoff = (wr * 64 + fr) * LDSPAD + fkg;
    const int woff = (wc * 64 + fr) * LDSPAD + fkg;

    f32x4 acc[4][4];
#pragma unroll
    for (int i = 0; i < 4; i++)
#pragma unroll
        for (int j = 0; j < 4; j++) acc[i][j] = {0.f, 0.f, 0.f, 0.f};

    // preload chunk 0
    float4 pa[4];
    uint4  pw[4];
#pragma unroll
    for (int i = 0; i < 4; i++) pa[i] = *(const float4*)&arow[sc + i * 4];
#pragma unroll
    for (int i = 0; i < 4; i++) pw[i] = *(const uint4*)&wrow[i * 8];

    for (int k0 = 0; k0 < KDIM; k0 += 32) {
        // ---- convert + write staged regs to LDS ----
        {
            unsigned hw[8], lw[8];
#pragma unroll
            for (int i = 0; i < 4; i++) {
                unsigned short h0, l0, h1, l1;
                split_bf16(pa[i].x, h0, l0);
                split_bf16(pa[i].y, h1, l1);
                hw[i * 2 + 0] = (unsigned)h0 | ((unsigned)h1 << 16);
                lw[i * 2 + 0] = (unsigned)l0 | ((unsigned)l1 << 16);
                split_bf16(pa[i].z, h0, l0);
                split_bf16(pa[i].w, h1, l1);
                hw[i * 2 + 1] = (unsigned)h0 | ((unsigned)h1 << 16);
                lw[i * 2 + 1] = (unsigned)l0 | ((unsigned)l1 << 16);
            }
            *(uint4*)&AhS[sr * LDSPAD + sc]     = (uint4){hw[0], hw[1], hw[2], hw[3]};
            *(uint4*)&AhS[sr * LDSPAD + sc + 8] = (uint4){hw[4], hw[5], hw[6], hw[7]};
            *(uint4*)&AlS[sr * LDSPAD + sc]     = (uint4){lw[0], lw[1], lw[2], lw[3]};
            *(uint4*)&AlS[sr * LDSPAD + sc + 8] = (uint4){lw[4], lw[5], lw[6], lw[7]};
#pragma unroll
            for (int i = 0; i < 4; i++)
                *(uint4*)&wdst[wn * LDSPAD + i * 8] = pw[i];
        }
        __syncthreads();

        // ---- preload next chunk (hides HBM latency under MFMA) ----
        if (k0 + 32 < KDIM) {
#pragma unroll
            for (int i = 0; i < 4; i++) pa[i] = *(const float4*)&arow[k0 + 32 + sc + i * 4];
#pragma unroll
            for (int i = 0; i < 4; i++) pw[i] = *(const uint4*)&wrow[k0 + 32 + i * 8];
        }

        // ---- fragments + MFMA ----
        bf16x8 ah[4], al[4], wh[4], wl[4];
#pragma unroll
        for (int i = 0; i < 4; i++) {
            ah[i] = *(const bf16x8*)&AhS[aoff + i * 16 * LDSPAD];
            al[i] = *(const bf16x8*)&AlS[aoff + i * 16 * LDSPAD];
        }
#pragma unroll
        for (int j = 0; j < 4; j++) {
            wh[j] = *(const bf16x8*)&WhS[woff + j * 16 * LDSPAD];
            wl[j] = *(const bf16x8*)&WlS[woff + j * 16 * LDSPAD];
        }
#pragma unroll
        for (int i = 0; i < 4; i++)
#pragma unroll
            for (int j = 0; j < 4; j++) {
                acc[i][j] = __builtin_amdgcn_mfma_f32_16x16x32_bf16(ah[i], wh[j], acc[i][j], 0, 0, 0);
                acc[i][j] = __builtin_amdgcn_mfma_f32_16x16x32_bf16(ah[i], wl[j], acc[i][j], 0, 0, 0);
                acc[i][j] = __builtin_amdgcn_mfma_f32_16x16x32_bf16(al[i], wh[j], acc[i][j], 0, 0, 0);
            }
        __syncthreads();
    }

    // ---- epilogue: C/D layout col = lane&15, row = (lane>>4)*4 + reg ----
#pragma unroll
    for (int j = 0; j < 4; j++) {
        const int col = col0 + wc * 64 + j * 16 + fr;
        const float bv = bias ? bias[col] : 0.f;
#pragma unroll
        for (int i = 0; i < 4; i++) {
            const int rbase = row0 + wr * 64 + i * 16 + (lane >> 4) * 4;
#pragma unroll
            for (int r = 0; r < 4; r++) {
                float v = acc[i][j][r] + bv;
                if constexpr (RELU) v = fmaxf(v, 0.f);
                const size_t off = (size_t)(rbase + r) * NDIM + col;
                C[off] = v;
                if constexpr (PROJ) {
                    float xv = xres[off];
                    out_ar[off] = (atype[rbase + r] == 0) ? xv + v : xv;
                }
            }
        }
    }
}

// ---------------------------------------------------------------------------
// JAX threefry2x32 with key (0, 42)
// ---------------------------------------------------------------------------
__device__ __forceinline__ void threefry2x32_k42(unsigned int& x0, unsigned int& x1)
{
    const unsigned int ks0 = 0u;
    const unsigned int ks1 = 42u;
    const unsigned int ks2 = 0x1BD11BDAu ^ 42u;
    x0 += ks0; x1 += ks1;
#define TFR(r) { x0 += x1; x1 = (x1 << (r)) | (x1 >> (32 - (r))); x1 ^= x0; }
    TFR(13) TFR(15) TFR(26) TFR(6)
    x0 += ks1; x1 += ks2 + 1u;
    TFR(17) TFR(29) TFR(16) TFR(24)
    x0 += ks2; x1 += ks0 + 2u;
    TFR(13) TFR(15) TFR(26) TFR(6)
    x0 += ks0; x1 += ks1 + 3u;
    TFR(17) TFR(29) TFR(16) TFR(24)
    x0 += ks1; x1 += ks2 + 4u;
    TFR(13) TFR(15) TFR(26) TFR(6)
    x0 += ks2; x1 += ks0 + 5u;
#undef TFR
}

// ---------------------------------------------------------------------------
// logits via algebraic rewrite: logit[s,m] = u[s].Hk[s,m] + q[s].bk2
// (u = Wk2 @ q). Softmax + gumbel-argmax, plus top-2 gap for cleanup.
// ---------------------------------------------------------------------------
__global__ __launch_bounds__(256)
void logits_kernel(const float* __restrict__ u, const float* __restrict__ Hk,
                   const float* __restrict__ q, const float* __restrict__ bk2,
                   const int* __restrict__ mask,
                   float* __restrict__ out_logits, float* __restrict__ out_policy,
                   float* __restrict__ out_index, float* __restrict__ gaps,
                   int t0)
{
    const int tl   = blockIdx.x * 256 + threadIdx.x;   // quarter-local move row
    const int t    = t0 + tl;                          // global move row
    const int slot = t >> 2;
    const int m    = t & 3;

    const float4* up = (const float4*)&u[(size_t)slot * F2_];
    const float4* hp = (const float4*)&Hk[(size_t)tl * F2_];
    double dot = 0.0;
#pragma unroll
    for (int i = 0; i < 64; i++) {
        float4 a = up[i], b = hp[i];
        dot += (double)a.x * b.x; dot += (double)a.y * b.y;
        dot += (double)a.z * b.z; dot += (double)a.w * b.w;
    }
    {
        const float4* qp = (const float4*)&q[(size_t)slot * F4_];
        const float4* bp = (const float4*)bk2;
        double qb = 0.0;
#pragma unroll
        for (int i = 0; i < 32; i++) {
            float4 a = qp[i], b = bp[i];
            qb += (double)a.x * b.x; qb += (double)a.y * b.y;
            qb += (double)a.z * b.z; qb += (double)a.w * b.w;
        }
        dot += qb;
    }

    const bool legal = (mask[t] != 0);

    double lmin = fmin(dot, __shfl_xor(dot, 1));
    lmin = fmin(lmin, __shfl_xor(lmin, 2));
    const double lm = legal ? dot : lmin;
    double lmax = fmax(lm, __shfl_xor(lm, 1));
    lmax = fmax(lmax, __shfl_xor(lmax, 2));
    const double e = legal ? exp(lm - lmax) : 0.0;
    double esum = e + __shfl_xor(e, 1);
    esum += __shfl_xor(esum, 2);
    const double policy = e / esum;

    out_logits[t] = (float)dot;
    out_policy[t] = (float)policy;

    const double sl = (policy > 0.0) ? log(policy) : -1e30;

    unsigned int x0 = 0u;
    unsigned int x1 = (unsigned int)t;
    threefry2x32_k42(x0, x1);
    const unsigned int bits = x0 ^ x1;

    const float f  = __uint_as_float(0x3f800000u | (bits >> 9)) - 1.0f;
    const float uf = fmaxf(1.17549435e-38f, f);
    const double g = -log(-log((double)uf));
    const double v = sl + g;

    // argmax over 4 lanes, lowest index wins ties
    int    best = m;
    double bv   = v;
    {
        double ov = __shfl_xor(bv, 1); int oi = __shfl_xor(best, 1);
        if (ov > bv || (ov == bv && oi < best)) { bv = ov; best = oi; }
        ov = __shfl_xor(bv, 2); oi = __shfl_xor(best, 2);
        if (ov > bv || (ov == bv && oi < best)) { bv = ov; best = oi; }
    }

    // top-2 gap of gumbel scores (for near-tie cleanup)
    double a1 = fmax(v, __shfl_xor(v, 1));
    double b1 = fmin(v, __shfl_xor(v, 1));
    double a2 = __shfl_xor(a1, 2);
    double b2 = __shfl_xor(b1, 2);
    double top2 = (a1 >= a2) ? fmax(a2, b1) : fmax(a1, b2);
    double top1 = fmax(a1, a2);

    if (m == 0) {
        out_index[slot] = (float)best;
        gaps[slot] = (float)(top1 - top2);
    }
}

// ---------------------------------------------------------------------------
// near-tie cleanup, stage A: compact slot list (single block, LDS counter)
// ---------------------------------------------------------------------------
#define TAU_ 3e-3f

__global__ __launch_bounds__(1024)
void compact_kernel(const float* __restrict__ gaps,
                    int* __restrict__ cnt, int* __restrict__ list)
{
    __shared__ int c;
    if (threadIdx.x == 0) c = 0;
    __syncthreads();
    for (int s = threadIdx.x; s < R_; s += 1024) {
        if (gaps[s] < TAU_) list[atomicAdd(&c, 1)] = s;
    }
    __syncthreads();
    if (threadIdx.x == 0) *cnt = c;
}

// ---------------------------------------------------------------------------
// near-tie cleanup, stage B: exact f64 recompute, throughput-structured.
// One slot per block iteration; weights staged through LDS with coalesced
// float4 loads; f64 FMAs from LDS with independent accumulator chains.
// ---------------------------------------------------------------------------
__global__ __launch_bounds__(256)
void cleanup2_kernel(const float* __restrict__ x, const float* __restrict__ moves,
                     const int* __restrict__ mask,
                     const float* __restrict__ Wq1, const float* __restrict__ bq1,
                     const float* __restrict__ Wq2, const float* __restrict__ bq2,
                     const float* __restrict__ Wk1, const float* __restrict__ bk1,
                     const float* __restrict__ Wk2, const float* __restrict__ bk2,
                     const int* __restrict__ cnt, const int* __restrict__ list,
                     float* __restrict__ out_index)
{
    __shared__ float  xs[512];
    __shared__ float  mvs[1024];        // 4 x 256 move rows
    __shared__ float  ws[16 * 256];     // staged weight chunk (16 KB)
    __shared__ double h1q[256];
    __shared__ double h1k[4][256];
    __shared__ double qv[128];
    __shared__ double kv[4][128];
    __shared__ double wred[8];

    const int j = threadIdx.x;
    const int n = *cnt;

    for (int ii = blockIdx.x; ii < n; ii += gridDim.x) {
        const int s = list[ii];
        __syncthreads();   // protect LDS reuse across slot iterations

        // stage x row (512 f32) + all 4 move rows (1024 f32)
        *(float2*)&xs[j * 2] = *(const float2*)&x[(size_t)s * F_ + j * 2];
        ((float4*)mvs)[j] = ((const float4*)&moves[(size_t)s * 4 * F2_])[j];

        // ---- h1q[j] = relu(x . Wq1[:,j] + bq1[j]), K=512, chunks of 16 ----
        double a0 = 0.0, a1 = 0.0;
        for (int c0 = 0; c0 < 512; c0 += 16) {
            __syncthreads();
#pragma unroll
            for (int u = 0; u < 4; u++) {
                int idx = u * 256 + j;
                int r = idx >> 6, c4 = (idx & 63) * 4;
                *(float4*)&ws[r * 256 + c4] = *(const float4*)&Wq1[(size_t)(c0 + r) * F2_ + c4];
            }
            __syncthreads();
#pragma unroll
            for (int c = 0; c < 16; c += 2) {
                a0 += (double)xs[c0 + c]     * (double)ws[c * 256 + j];
                a1 += (double)xs[c0 + c + 1] * (double)ws[(c + 1) * 256 + j];
            }
        }
        h1q[j] = fmax(a0 + a1 + (double)bq1[j], 0.0);

        // ---- qv[j<128] = h1q . Wq2[:,j] + bq2[j], K=256, chunks of 32 ----
        double q0 = 0.0, q1 = 0.0;
        for (int c0 = 0; c0 < 256; c0 += 32) {
            __syncthreads();
#pragma unroll
            for (int u = 0; u < 4; u++) {
                int idx = u * 256 + j;
                int r = idx >> 5, c4 = (idx & 31) * 4;
                *(float4*)&ws[r * 128 + c4] = *(const float4*)&Wq2[(size_t)(c0 + r) * F4_ + c4];
            }
            __syncthreads();
            if (j < 128) {
#pragma unroll
                for (int c = 0; c < 32; c += 2) {
                    q0 += h1q[c0 + c]     * (double)ws[c * 128 + j];
                    q1 += h1q[c0 + c + 1] * (double)ws[(c + 1) * 128 + j];
                }
            }
        }
        if (j < 128) qv[j] = q0 + q1 + (double)bq2[j];

        // ---- h1k[m][j] for all 4 moves, K=256, shared Wk1 chunks ----
        double k0 = 0.0, k1 = 0.0, k2 = 0.0, k3 = 0.0;
        for (int c0 = 0; c0 < 256; c0 += 16) {
            __syncthreads();
#pragma unroll
            for (int u = 0; u < 4; u++) {
                int idx = u * 256 + j;
                int r = idx >> 6, c4 = (idx & 63) * 4;
                *(float4*)&ws[r * 256 + c4] = *(const float4*)&Wk1[(size_t)(c0 + r) * F2_ + c4];
            }
            __syncthreads();
#pragma unroll
            for (int c = 0; c < 16; c++) {
                double w = (double)ws[c * 256 + j];
                k0 += (double)mvs[0 * 256 + c0 + c] * w;
                k1 += (double)mvs[1 * 256 + c0 + c] * w;
                k2 += (double)mvs[2 * 256 + c0 + c] * w;
                k3 += (double)mvs[3 * 256 + c0 + c] * w;
            }
        }
        h1k[0][j] = fmax(k0 + (double)bk1[j], 0.0);
        h1k[1][j] = fmax(k1 + (double)bk1[j], 0.0);
        h1k[2][j] = fmax(k2 + (double)bk1[j], 0.0);
        h1k[3][j] = fmax(k3 + (double)bk1[j], 0.0);

        // ---- kv[m][jj] = h1k[m] . Wk2[:,jj] + bk2[jj]; 2 moves per thread ----
        const int jj = j & 127, mh = j >> 7;
        double v0 = 0.0, v1 = 0.0;
        for (int c0 = 0; c0 < 256; c0 += 32) {
            __syncthreads();
#pragma unroll
            for (int u = 0; u < 4; u++) {
                int idx = u * 256 + j;
                int r = idx >> 5, c4 = (idx & 31) * 4;
                *(float4*)&ws[r * 128 + c4] = *(const float4*)&Wk2[(size_t)(c0 + r) * F4_ + c4];
            }
            __syncthreads();
#pragma unroll
            for (int c = 0; c < 32; c++) {
                double w = (double)ws[c * 128 + jj];
                v0 += h1k[mh][c0 + c]     * w;
                v1 += h1k[mh + 2][c0 + c] * w;
            }
        }
        kv[mh][jj]     = v0 + (double)bk2[jj];
        kv[mh + 2][jj] = v1 + (double)bk2[jj];
        __syncthreads();

        // ---- 4 dots of length 128: wave w handles move w ----
        {
            const int w = j >> 6, l = j & 63;
            double d = qv[l] * kv[w][l] + qv[l + 64] * kv[w][l + 64];
#pragma unroll
            for (int o = 32; o; o >>= 1) d += __shfl_xor(d, o);
            if (l == 0) wred[w] = d;
        }
        __syncthreads();

        // ---- exact sampling (thread 0) ----
        if (j == 0) {
            double dotS[4];
#pragma unroll
            for (int mv = 0; mv < 4; mv++) dotS[mv] = wred[mv];
            double lmin = dotS[0];
#pragma unroll
            for (int mv = 1; mv < 4; mv++) lmin = fmin(lmin, dotS[mv]);
            double lm[4]; bool lg[4];
            double lmax = -1e300;
#pragma unroll
            for (int mv = 0; mv < 4; mv++) {
                lg[mv] = (mask[(size_t)s * 4 + mv] != 0);
                lm[mv] = lg[mv] ? dotS[mv] : lmin;
                lmax = fmax(lmax, lm[mv]);
            }
            double e[4]; double esum = 0.0;
#pragma unroll
            for (int mv = 0; mv < 4; mv++) {
                e[mv] = lg[mv] ? exp(lm[mv] - lmax) : 0.0;
                esum += e[mv];
            }
            int best = -1; double bv = -1e308;
#pragma unroll
            for (int mv = 0; mv < 4; mv++) {
                double pol = e[mv] / esum;
                double sl = (pol > 0.0) ? log(pol) : -1e30;
                unsigned xx0 = 0u, xx1 = (unsigned)(s * 4 + mv);
                threefry2x32_k42(xx0, xx1);
                unsigned bits = xx0 ^ xx1;
                float fu = __uint_as_float(0x3f800000u | (bits >> 9)) - 1.0f;
                float uf = fmaxf(1.17549435e-38f, fu);
                double g = -log(-log((double)uf));
                double v = sl + g;
                if (v > bv) { bv = v; best = mv; }
            }
            out_index[s] = (float)best;
        }
    }
}

// ===========================================================================
// LEGACY FALLBACK (previous verified kernels) — used if d_ws is too small
// ===========================================================================
template<int KDIM>
__global__ __launch_bounds__(256, 3)
void mlp2_kernel(const float* __restrict__ A,
                 const float* __restrict__ W1, const float* __restrict__ b1,
                 const float* __restrict__ W2, const float* __restrict__ b2,
                 float* __restrict__ out)
{
    __shared__ float H[32][260];
    __shared__ float As[32][20];
    __shared__ float Bs[4096];

    const int tid  = threadIdx.x;
    const int row0 = blockIdx.x * 32;
    const int tx   = tid & 31;
    const int ty   = tid >> 5;

    float acc[4][8];
#pragma unroll
    for (int i = 0; i < 4; i++)
#pragma unroll
        for (int j = 0; j < 8; j++) acc[i][j] = 0.f;

    for (int k0 = 0; k0 < KDIM; k0 += 16) {
        {
            int r = tid >> 3;
            int c = (tid & 7) * 2;
            float2 v = *(const float2*)&A[(size_t)(row0 + r) * KDIM + k0 + c];
            *(float2*)&As[r][c] = v;
        }
        {
            int kk = tid >> 4;
            int c0 = (tid & 15) * 16;
            const float* src = &W1[(size_t)(k0 + kk) * F2_ + c0];
            float* dst = &Bs[kk * F2_ + c0];
#pragma unroll
            for (int j = 0; j < 4; j++) ((float4*)dst)[j] = ((const float4*)src)[j];
        }
        __syncthreads();
#pragma unroll
        for (int kk = 0; kk < 16; kk += 4) {
            float4 a[4];
#pragma unroll
            for (int i = 0; i < 4; i++) a[i] = *(const float4*)&As[ty * 4 + i][kk];
#pragma unroll
            for (int u = 0; u < 4; u++) {
                float4 w0 = *(const float4*)&Bs[(kk + u) * F2_ + tx * 8];
                float4 w1 = *(const float4*)&Bs[(kk + u) * F2_ + tx * 8 + 4];
#pragma unroll
                for (int i = 0; i < 4; i++) {
                    float av = ((const float*)&a[i])[u];
                    acc[i][0] += av * w0.x; acc[i][1] += av * w0.y;
                    acc[i][2] += av * w0.z; acc[i][3] += av * w0.w;
                    acc[i][4] += av * w1.x; acc[i][5] += av * w1.y;
                    acc[i][6] += av * w1.z; acc[i][7] += av * w1.w;
                }
            }
        }
        __syncthreads();
    }
    {
        float4 b1a = *(const float4*)&b1[tx * 8];
        float4 b1b = *(const float4*)&b1[tx * 8 + 4];
        const float bv[8] = {b1a.x, b1a.y, b1a.z, b1a.w, b1b.x, b1b.y, b1b.z, b1b.w};
#pragma unroll
        for (int i = 0; i < 4; i++) {
            float4 h0, h1;
            h0.x = fmaxf(acc[i][0] + bv[0], 0.f);
            h0.y = fmaxf(acc[i][1] + bv[1], 0.f);
            h0.z = fmaxf(acc[i][2] + bv[2], 0.f);
            h0.w = fmaxf(acc[i][3] + bv[3], 0.f);
            h1.x = fmaxf(acc[i][4] + bv[4], 0.f);
            h1.y = fmaxf(acc[i][5] + bv[5], 0.f);
            h1.z = fmaxf(acc[i][6] + bv[6], 0.f);
            h1.w = fmaxf(acc[i][7] + bv[7], 0.f);
            *(float4*)&H[ty * 4 + i][tx * 8]     = h0;
            *(float4*)&H[ty * 4 + i][tx * 8 + 4] = h1;
        }
    }
    __syncthreads();

    float acc2[4][4];
#pragma unroll
    for (int i = 0; i < 4; i++)
#pragma unroll
        for (int j = 0; j < 4; j++) acc2[i][j] = 0.f;

    for (int k0 = 0; k0 < F2_; k0 += 32) {
        {
            int kk = tid >> 3;
            int c0 = (tid & 7) * 16;
            const float* src = &W2[(size_t)(k0 + kk) * F4_ + c0];
            float* dst = &Bs[kk * F4_ + c0];
#pragma unroll
            for (int j = 0; j < 4; j++) ((float4*)dst)[j] = ((const float4*)src)[j];
        }
        __syncthreads();
#pragma unroll
        for (int kk = 0; kk < 32; kk += 4) {
            float4 h[4];
#pragma unroll
            for (int i = 0; i < 4; i++) h[i] = *(const float4*)&H[ty * 4 + i][k0 + kk];
#pragma unroll
            for (int u = 0; u < 4; u++) {
                float4 w = *(const float4*)&Bs[(kk + u) * F4_ + tx * 4];
#pragma unroll
                for (int i = 0; i < 4; i++) {
                    float hv = ((const float*)&h[i])[u];
                    acc2[i][0] += hv * w.x; acc2[i][1] += hv * w.y;
                    acc2[i][2] += hv * w.z; acc2[i][3] += hv * w.w;
                }
            }
        }
        __syncthreads();
    }
    {
        float4 bb = *(const float4*)&b2[tx * 4];
#pragma unroll
        for (int i = 0; i < 4; i++) {
            float4 o;
            o.x = acc2[i][0] + bb.x;
            o.y = acc2[i][1] + bb.y;
            o.z = acc2[i][2] + bb.z;
            o.w = acc2[i][3] + bb.w;
            *(float4*)&out[(size_t)(row0 + ty * 4 + i) * F4_ + tx * 4] = o;
        }
    }
}

__global__ __launch_bounds__(256)
void logits_sample_kernel(const float* __restrict__ Q, const float* __restrict__ Kv,
                          const int* __restrict__ mask,
                          float* __restrict__ out_logits, float* __restrict__ out_policy,
                          float* __restrict__ out_index)
{
    const int t    = blockIdx.x * 256 + threadIdx.x;
    const int slot = t >> 2;
    const int m    = t & 3;

    const float4* qp = (const float4*)&Q[(size_t)slot * F4_];
    const float4* kp = (const float4*)&Kv[(size_t)t * F4_];
    double dot = 0.0;
#pragma unroll
    for (int i = 0; i < 32; i++) {
        float4 a = qp[i], b = kp[i];
        dot += (double)a.x * b.x; dot += (double)a.y * b.y;
        dot += (double)a.z * b.z; dot += (double)a.w * b.w;
    }

    const bool legal = (mask[t] != 0);

    double lmin = fmin(dot, __shfl_xor(dot, 1));
    lmin = fmin(lmin, __shfl_xor(lmin, 2));
    const double lm = legal ? dot : lmin;
    double lmax = fmax(lm, __shfl_xor(lm, 1));
    lmax = fmax(lmax, __shfl_xor(lmax, 2));
    const double e = legal ? exp(lm - lmax) : 0.0;
    double esum = e + __shfl_xor(e, 1);
    esum += __shfl_xor(esum, 2);
    const double policy = e / esum;

    out_logits[t] = (float)dot;
    out_policy[t] = (float)policy;

    const double sl = (policy > 0.0) ? log(policy) : -1e30;

    unsigned int x0 = 0u;
    unsigned int x1 = (unsigned int)t;
    threefry2x32_k42(x0, x1);
    const unsigned int bits = x0 ^ x1;

    const float f  = __uint_as_float(0x3f800000u | (bits >> 9)) - 1.0f;
    const float uf = fmaxf(1.17549435e-38f, f);
    const double g = -log(-log((double)uf));
    const double v = sl + g;

    int    best = m;
    double bv   = v;
    {
        double ov = __shfl_xor(bv, 1); int oi = __shfl_xor(best, 1);
        if (ov > bv || (ov == bv && oi < best)) { bv = ov; best = oi; }
        ov = __shfl_xor(bv, 2); oi = __shfl_xor(best, 2);
        if (ov > bv || (ov == bv && oi < best)) { bv = ov; best = oi; }
    }
    if (m == 0) out_index[slot] = (float)best;
}

__global__ __launch_bounds__(256, 3)
void proj_kernel(const float* __restrict__ moves, const float* __restrict__ idxf,
                 const float* __restrict__ Wp, const float* __restrict__ bp,
                 const float* __restrict__ x, const int* __restrict__ atype,
                 float* __restrict__ out_ar, float* __restrict__ out_proj)
{
    __shared__ float As[32][260];
    __shared__ float Bs[32 * 128];

    const int tid  = threadIdx.x;
    const int row0 = blockIdx.x * 32;
    const int col0 = blockIdx.y * 128;
    const int tx   = tid & 31;
    const int ty   = tid >> 5;

#pragma unroll
    for (int it = 0; it < 8; it++) {
        int r = (tid >> 6) + it * 4;
        int c = (tid & 63) * 4;
        int slot = row0 + r;
        int mi = (int)idxf[slot];
        float4 v = *(const float4*)&moves[((size_t)slot * 4 + mi) * F2_ + c];
        *(float4*)&As[r][c] = v;
    }
    __syncthreads();

    float acc[4][4];
#pragma unroll
    for (int i = 0; i < 4; i++)
#pragma unroll
        for (int j = 0; j < 4; j++) acc[i][j] = 0.f;

    for (int k0 = 0; k0 < F2_; k0 += 32) {
        {
            int kk = tid >> 3;
            int c0 = (tid & 7) * 16;
            const float* src = &Wp[(size_t)(k0 + kk) * F_ + col0 + c0];
            float* dst = &Bs[kk * 128 + c0];
#pragma unroll
            for (int j = 0; j < 4; j++) ((float4*)dst)[j] = ((const float4*)src)[j];
        }
        __syncthreads();
#pragma unroll
        for (int kk = 0; kk < 32; kk += 4) {
            float4 h[4];
#pragma unroll
            for (int i = 0; i < 4; i++) h[i] = *(const float4*)&As[ty * 4 + i][k0 + kk];
#pragma unroll
            for (int u = 0; u < 4; u++) {
                float4 w = *(const float4*)&Bs[(kk + u) * 128 + tx * 4];
#pragma unroll
                for (int i = 0; i < 4; i++) {
                    float hv = ((const float*)&h[i])[u];
                    acc[i][0] += hv * w.x; acc[i][1] += hv * w.y;
                    acc[i][2] += hv * w.z; acc[i][3] += hv * w.w;
                }
            }
        }
        __syncthreads();
    }

    float4 bb = *(const float4*)&bp[col0 + tx * 4];
#pragma unroll
    for (int i = 0; i < 4; i++) {
        int row = row0 + ty * 4 + i;
        float4 p;
        p.x = acc[i][0] + bb.x;
        p.y = acc[i][1] + bb.y;
        p.z = acc[i][2] + bb.z;
        p.w = acc[i][3] + bb.w;
        size_t off = (size_t)row * F_ + col0 + tx * 4;
        *(float4*)&out_proj[off] = p;
        float4 a = *(const float4*)&x[off];
        bool valid = (atype[row] == 0);
        float4 r4;
        r4.x = valid ? a.x + p.x : a.x;
        r4.y = valid ? a.y + p.y : a.y;
        r4.z = valid ? a.z + p.z : a.z;
        r4.w = valid ? a.w + p.w : a.w;
        *(float4*)&out_ar[off] = r4;
    }
}

// ---------------------------------------------------------------------------
extern "C" void kernel_launch(void* const* d_in, const int* in_sizes, int n_in,
                              void* d_out, int out_size, void* d_ws, size_t ws_size,
                              hipStream_t stream)
{
    (void)in_sizes; (void)n_in; (void)out_size;

    const int*   atype = (const int*)d_in[0];
    const float* x     = (const float*)d_in[1];
    const float* moves = (const float*)d_in[2];
    const int*   mask  = (const int*)d_in[3];
    const float* Wq1   = (const float*)d_in[4];
    const float* bq1   = (const float*)d_in[5];
    const float* Wq2   = (const float*)d_in[6];
    const float* bq2   = (const float*)d_in[7];
    const float* Wk1   = (const float*)d_in[8];
    const float* bk1   = (const float*)d_in[9];
    const float* Wk2   = (const float*)d_in[10];
    const float* bk2   = (const float*)d_in[11];
    const float* Wp    = (const float*)d_in[12];
    const float* bp    = (const float*)d_in[13];

    float* out_logits = (float*)d_out;                   // [R_,4]
    float* out_policy = out_logits + RM_;                // [R_,4]
    float* out_index  = out_policy + RM_;                // [R_,1]
    float* out_ar     = out_index + R_;                  // [R_,512]
    float* out_proj   = out_ar + (size_t)R_ * F_;        // [R_,512]

    // Workspace: split-bf16 weight planes (1.5 MB) + gaps (128 KB)
    const size_t WS_NEED = (size_t)786432 * 2 + (size_t)R_ * 4;   // 1,703,936 B

    if (d_ws != nullptr && ws_size >= WS_NEED) {
        unsigned short* wq1h = (unsigned short*)d_ws;    // [256][512]
        unsigned short* wq1l = wq1h + 131072;
        unsigned short* wq2h = wq1l + 131072;            // [128][256]
        unsigned short* wq2l = wq2h + 32768;
        unsigned short* wk1h = wq2l + 32768;             // [256][256]
        unsigned short* wk1l = wk1h + 65536;
        unsigned short* wk2h = wk1l + 65536;             // [256][128] (= Wk2 natural, W for u-GEMM)
        unsigned short* wk2l = wk2h + 32768;
        unsigned short* wph  = wk2l + 32768;             // [512][256]
        unsigned short* wpl  = wph + 131072;
        float* gaps = (float*)(wpl + 131072);

        // scratch carved out of d_out regions that proj overwrites last:
        float* Hq = out_ar;                 // [32768][256]  (32 MB)
        float* qv = out_ar + 8388608;       // [32768][128]  (16 MB)
        float* uv = out_proj;               // [32768][256]  (32 MB)
        float* Hk = out_ar;                 // quarter scratch [32768][256] (reuses Hq region)
        // free tail of out_ar (floats [12.58M, 16.78M)): compaction scratch
        int* cl_cnt  = (int*)(out_ar + 12582912);
        int* cl_list = cl_cnt + 16;

        // ---- repack weights to [N][K] bf16 hi/lo planes ----
        repack_kernel<true ><<<512, 256, 0, stream>>>(Wq1, F2_, 9, wq1h, wq1l);
        repack_kernel<true ><<<128, 256, 0, stream>>>(Wq2, F4_, 8, wq2h, wq2l);
        repack_kernel<true ><<<256, 256, 0, stream>>>(Wk1, F2_, 8, wk1h, wk1l);
        repack_kernel<false><<<128, 256, 0, stream>>>(Wk2, F4_, 7, wk2h, wk2l);
        repack_kernel<true ><<<512, 256, 0, stream>>>(Wp,  F_,  8, wph,  wpl);

        // ---- Q path ----
        dim3 g1(R_ / 128, 2);
        gemm_bf16s<512, 256, true,  false><<<g1, 256, 0, stream>>>(
            x, wq1h, wq1l, bq1, Hq, nullptr, nullptr, nullptr, nullptr, nullptr);
        dim3 g2(R_ / 128, 1);
        gemm_bf16s<256, 128, false, false><<<g2, 256, 0, stream>>>(
            Hq, wq2h, wq2l, bq2, qv, nullptr, nullptr, nullptr, nullptr, nullptr);
        dim3 g3(R_ / 128, 2);
        gemm_bf16s<128, 256, false, false><<<g3, 256, 0, stream>>>(
            qv, wk2h, wk2l, nullptr, uv, nullptr, nullptr, nullptr, nullptr, nullptr);

        // ---- K path in 4 quarters (Hk scratch = 32 MB) + logits ----
        for (int qi = 0; qi < 4; qi++) {
            const float* mseg = moves + (size_t)qi * 32768 * F2_;
            gemm_bf16s<256, 256, true, false><<<g3, 256, 0, stream>>>(
                mseg, wk1h, wk1l, bk1, Hk, nullptr, nullptr, nullptr, nullptr, nullptr);
            logits_kernel<<<128, 256, 0, stream>>>(
                uv, Hk, qv, bk2, mask, out_logits, out_policy, out_index, gaps, qi * 32768);
        }

        // ---- near-tie exact recompute: compact then throughput recompute ----
        compact_kernel<<<1, 1024, 0, stream>>>(gaps, cl_cnt, cl_list);
        cleanup2_kernel<<<128, 256, 0, stream>>>(
            x, moves, mask, Wq1, bq1, Wq2, bq2, Wk1, bk1, Wk2, bk2,
            cl_cnt, cl_list, out_index);

        // ---- gather + projection + ar_out epilogue ----
        dim3 gp(R_ / 128, 4);
        gemm_bf16s<256, 512, false, true><<<gp, 256, 0, stream>>>(
            nullptr, wph, wpl, bp, out_proj, out_index, moves, x, atype, out_ar);
    } else {
        // -------- legacy fp32 path (previous verified kernel) --------
        float* Q  = out_proj;
        float* Kv = out_ar;

        mlp2_kernel<F_><<<R_ / 32, 256, 0, stream>>>(x, Wq1, bq1, Wq2, bq2, Q);
        mlp2_kernel<F2_><<<RM_ / 32, 256, 0, stream>>>(moves, Wk1, bk1, Wk2, bk2, Kv);
        logits_sample_kernel<<<RM_ / 256, 256, 0, stream>>>(Q, Kv, mask,
                                                            out_logits, out_policy, out_index);
        dim3 pgrid(R_ / 32, 4);
        proj_kernel<<<pgrid, 256, 0, stream>>>(moves, out_index, Wp, bp, x, atype,
                                               out_ar, out_proj);
    }
}

// Round 3
// 731.885 us; speedup vs baseline: 1.4348x; 1.1237x over previous
//
#include <hip/hip_runtime.h>

// Problem constants
#define B_   64
#define T_   512
#define F_   512
#define F2_  256
#define F4_  128
#define R_   32768      // B*T slots
#define RM_  131072     // R*4 move rows

typedef __attribute__((ext_vector_type(8))) short bf16x8;
typedef __attribute__((ext_vector_type(4))) float f32x4;

// ---------------------------------------------------------------------------
// split fp32 -> (hi, lo) bf16 with RNE; a ~= hi + lo to ~16-17 mantissa bits
// ---------------------------------------------------------------------------
__device__ __forceinline__ void split_bf16(float a, unsigned short& h, unsigned short& l)
{
    unsigned x  = __float_as_uint(a);
    unsigned rh = x + 0x7FFFu + ((x >> 16) & 1u);
    unsigned short hs = (unsigned short)(rh >> 16);
    float fh = __uint_as_float((unsigned)hs << 16);
    float r  = a - fh;                    // exact (Sterbenz-range)
    unsigned y  = __float_as_uint(r);
    unsigned rl = y + 0x7FFFu + ((y >> 16) & 1u);
    h = hs;
    l = (unsigned short)(rl >> 16);
}

// ---------------------------------------------------------------------------
// weight repack: W[k][n] f32 -> Wt_hi[n][k], Wt_lo[n][k] bf16 planes
// TRANS=false: src already [n][k]
// ---------------------------------------------------------------------------
template<bool TRANS>
__global__ __launch_bounds__(256)
void repack_kernel(const float* __restrict__ src, int N, int kbits,
                   unsigned short* __restrict__ hi, unsigned short* __restrict__ lo)
{
    int idx = blockIdx.x * 256 + threadIdx.x;
    int K = 1 << kbits;
    int k = idx & (K - 1);
    int n = idx >> kbits;
    float v = TRANS ? src[(size_t)k * N + n] : src[idx];
    unsigned short h, l;
    split_bf16(v, h, l);
    hi[idx] = h; lo[idx] = l;
}

// ---------------------------------------------------------------------------
// Split-bf16 MFMA GEMM: C[M][NDIM] = act(A[M][KDIM] @ W + bias)
// A: f32, converted to (hi,lo) bf16 during staging. W: pre-split bf16 [N][K].
// 3-product emulation: Ah*Wh + Ah*Wl + Al*Wh.
// 128x128 tile, BK=32, 4 waves (2x2), 16x16x32 bf16 MFMA.
// DOUBLE-BUFFERED LDS, one raw s_barrier per K-step (no vmcnt drain):
//   iter t: ds_read frags buf[t&1] -> MFMA -> convert+write buf[t^1] (tile t+1)
//           -> issue global loads (tile t+2) -> lgkmcnt(0); s_barrier
// PROJ: gather A rows from moves via idxf; fused ar_out epilogue.
// DOT : no C write; logit partial = sum_col u[slot][col]*relu(acc+bias[col]),
//       reduced per row (shfl + LDS), written to part[blockIdx.y][row].
// ---------------------------------------------------------------------------
#define LDSPAD 40

template<int KDIM, int NDIM, bool RELU, bool PROJ, bool DOT>
__global__ __launch_bounds__(256, 2)
void gemm_bf16s(const float* __restrict__ A,
                const unsigned short* __restrict__ Wh,
                const unsigned short* __restrict__ Wl,
                const float* __restrict__ bias,
                float* __restrict__ C,
                const float* __restrict__ idxf,
                const float* __restrict__ moves,
                const float* __restrict__ xres,
                const int*   __restrict__ atype,
                float* __restrict__ out_ar,
                const float* __restrict__ udot,
                double* __restrict__ part)
{
    constexpr int BUFE = 128 * LDSPAD;           // shorts per buffer
    __shared__ __align__(16) unsigned short AhS[2 * BUFE];
    __shared__ __align__(16) unsigned short AlS[2 * BUFE];
    __shared__ __align__(16) unsigned short WhS[2 * BUFE];
    __shared__ __align__(16) unsigned short WlS[2 * BUFE];

    const int tid  = threadIdx.x;
    const int lane = tid & 63;
    const int wid  = tid >> 6;
    const int wr   = wid >> 1;
    const int wc   = wid & 1;
    const int row0 = blockIdx.x * 128;
    const int col0 = blockIdx.y * 128;

    // ---- staging coordinates ----
    const int sr = tid >> 1;           // A stage row 0..127
    const int sc = (tid & 1) * 16;     // A stage k offset within chunk
    const float* arow;
    if constexpr (PROJ) {
        const int slot = row0 + sr;
        const int mi = (int)idxf[slot];
        arow = moves + ((size_t)slot * 4 + mi) * KDIM;
    } else {
        arow = A + (size_t)(row0 + sr) * KDIM;
    }
    const int wn = tid & 127;
    const unsigned short* wrow = ((tid >> 7) ? Wl : Wh) + (size_t)(col0 + wn) * KDIM;

    // ---- fragment LDS offsets (ushort units) ----
    const int fr   = lane & 15;
    const int fkg  = (lane >> 4) * 8;
    const int aoff = (wr * 64 + fr) * LDSPAD + fkg;
    const int woff = (wc * 64 + fr) * LDSPAD + fkg;

    float4 pa[4];
    uint4  pw[4];

    auto issue_loads = [&](int k0) {
#pragma unroll
        for (int i = 0; i < 4; i++) pa[i] = *(const float4*)&arow[k0 + sc + i * 4];
#pragma unroll
        for (int i = 0; i < 4; i++) pw[i] = *(const uint4*)&wrow[k0 + i * 8];
    };

    auto convert_write = [&](int b) {
        unsigned hw[8], lw[8];
#pragma unroll
        for (int i = 0; i < 4; i++) {
            unsigned short h0, l0, h1, l1;
            split_bf16(pa[i].x, h0, l0);
            split_bf16(pa[i].y, h1, l1);
            hw[i * 2 + 0] = (unsigned)h0 | ((unsigned)h1 << 16);
            lw[i * 2 + 0] = (unsigned)l0 | ((unsigned)l1 << 16);
            split_bf16(pa[i].z, h0, l0);
            split_bf16(pa[i].w, h1, l1);
            hw[i * 2 + 1] = (unsigned)h0 | ((unsigned)h1 << 16);
            lw[i * 2 + 1] = (unsigned)l0 | ((unsigned)l1 << 16);
        }
        unsigned short* ahp = AhS + b * BUFE;
        unsigned short* alp = AlS + b * BUFE;
        *(uint4*)&ahp[sr * LDSPAD + sc]     = (uint4){hw[0], hw[1], hw[2], hw[3]};
        *(uint4*)&ahp[sr * LDSPAD + sc + 8] = (uint4){hw[4], hw[5], hw[6], hw[7]};
        *(uint4*)&alp[sr * LDSPAD + sc]     = (uint4){lw[0], lw[1], lw[2], lw[3]};
        *(uint4*)&alp[sr * LDSPAD + sc + 8] = (uint4){lw[4], lw[5], lw[6], lw[7]};
        unsigned short* wp = ((tid >> 7) ? WlS : WhS) + b * BUFE;
#pragma unroll
        for (int i = 0; i < 4; i++)
            *(uint4*)&wp[wn * LDSPAD + i * 8] = pw[i];
    };

    f32x4 acc[4][4];
#pragma unroll
    for (int i = 0; i < 4; i++)
#pragma unroll
        for (int j = 0; j < 4; j++) acc[i][j] = {0.f, 0.f, 0.f, 0.f};

    // ---- prologue: tile0 -> buf0; issue tile1 loads ----
    issue_loads(0);
    convert_write(0);
    issue_loads(32);
    asm volatile("s_waitcnt lgkmcnt(0)" ::: "memory");
    __builtin_amdgcn_s_barrier();
    __builtin_amdgcn_sched_barrier(0);

    constexpr int NT = KDIM / 32;
    for (int t = 0; t < NT; ++t) {
        const int cur = t & 1;
        const unsigned short* ab  = AhS + cur * BUFE;
        const unsigned short* lb  = AlS + cur * BUFE;
        const unsigned short* whb = WhS + cur * BUFE;
        const unsigned short* wlb = WlS + cur * BUFE;

        bf16x8 fah[4], fal[4], fwh[4], fwl[4];
#pragma unroll
        for (int i = 0; i < 4; i++) {
            fah[i] = *(const bf16x8*)&ab[aoff + i * 16 * LDSPAD];
            fal[i] = *(const bf16x8*)&lb[aoff + i * 16 * LDSPAD];
        }
#pragma unroll
        for (int j = 0; j < 4; j++) {
            fwh[j] = *(const bf16x8*)&whb[woff + j * 16 * LDSPAD];
            fwl[j] = *(const bf16x8*)&wlb[woff + j * 16 * LDSPAD];
        }
#pragma unroll
        for (int i = 0; i < 4; i++)
#pragma unroll
            for (int j = 0; j < 4; j++) {
                acc[i][j] = __builtin_amdgcn_mfma_f32_16x16x32_bf16(fah[i], fwh[j], acc[i][j], 0, 0, 0);
                acc[i][j] = __builtin_amdgcn_mfma_f32_16x16x32_bf16(fah[i], fwl[j], acc[i][j], 0, 0, 0);
                acc[i][j] = __builtin_amdgcn_mfma_f32_16x16x32_bf16(fal[i], fwh[j], acc[i][j], 0, 0, 0);
            }
        __builtin_amdgcn_sched_barrier(0);

        if (t + 1 < NT) convert_write((t + 1) & 1);   // waits tile t+1 loads (vmcnt)
        if (t + 2 < NT) issue_loads((t + 2) * 32);    // stays in flight across barrier

        asm volatile("s_waitcnt lgkmcnt(0)" ::: "memory");
        __builtin_amdgcn_s_barrier();
        __builtin_amdgcn_sched_barrier(0);
    }

    if constexpr (DOT) {
        // logit partial: sum over this block's 128 cols of u[slot][col]*Hk
        double pv[4][4];
#pragma unroll
        for (int i = 0; i < 4; i++) {
            const int lrow = wr * 64 + i * 16 + ((lane >> 4) << 2);
            const int slot = (row0 + lrow) >> 2;
            double pr0 = 0.0, pr1 = 0.0, pr2 = 0.0, pr3 = 0.0;
#pragma unroll
            for (int j = 0; j < 4; j++) {
                const int col = col0 + wc * 64 + j * 16 + fr;
                const double u = (double)udot[(size_t)slot * F2_ + col];
                const float bv = bias[col];
                pr0 += (double)fmaxf(acc[i][j][0] + bv, 0.f) * u;
                pr1 += (double)fmaxf(acc[i][j][1] + bv, 0.f) * u;
                pr2 += (double)fmaxf(acc[i][j][2] + bv, 0.f) * u;
                pr3 += (double)fmaxf(acc[i][j][3] + bv, 0.f) * u;
            }
            pv[i][0] = pr0; pv[i][1] = pr1; pv[i][2] = pr2; pv[i][3] = pr3;
        }
#pragma unroll
        for (int o = 1; o <= 8; o <<= 1)
#pragma unroll
            for (int i = 0; i < 4; i++)
#pragma unroll
                for (int r = 0; r < 4; r++)
                    pv[i][r] += __shfl_xor(pv[i][r], o);

        double* red = (double*)AhS;     // 128 doubles, reuse staging LDS
        if (wc == 0 && fr == 0) {
#pragma unroll
            for (int i = 0; i < 4; i++)
#pragma unroll
                for (int r = 0; r < 4; r++)
                    red[wr * 64 + i * 16 + ((lane >> 4) << 2) + r] = pv[i][r];
        }
        __syncthreads();
        if (wc == 1 && fr == 0) {
#pragma unroll
            for (int i = 0; i < 4; i++)
#pragma unroll
                for (int r = 0; r < 4; r++)
                    red[wr * 64 + i * 16 + ((lane >> 4) << 2) + r] += pv[i][r];
        }
        __syncthreads();
        if (tid < 128) part[(size_t)blockIdx.y * RM_ + row0 + tid] = red[tid];
        return;
    }

    // ---- epilogue: C/D layout col = lane&15, row = (lane>>4)*4 + reg ----
#pragma unroll
    for (int j = 0; j < 4; j++) {
        const int col = col0 + wc * 64 + j * 16 + fr;
        const float bv = bias ? bias[col] : 0.f;
#pragma unroll
        for (int i = 0; i < 4; i++) {
            const int rbase = row0 + wr * 64 + i * 16 + (lane >> 4) * 4;
#pragma unroll
            for (int r = 0; r < 4; r++) {
                float v = acc[i][j][r] + bv;
                if constexpr (RELU) v = fmaxf(v, 0.f);
                const size_t off = (size_t)(rbase + r) * NDIM + col;
                C[off] = v;
                if constexpr (PROJ) {
                    float xv = xres[off];
                    out_ar[off] = (atype[rbase + r] == 0) ? xv + v : xv;
                }
            }
        }
    }
}

// ---------------------------------------------------------------------------
// JAX threefry2x32 with key (0, 42)
// ---------------------------------------------------------------------------
__device__ __forceinline__ void threefry2x32_k42(unsigned int& x0, unsigned int& x1)
{
    const unsigned int ks0 = 0u;
    const unsigned int ks1 = 42u;
    const unsigned int ks2 = 0x1BD11BDAu ^ 42u;
    x0 += ks0; x1 += ks1;
#define TFR(r) { x0 += x1; x1 = (x1 << (r)) | (x1 >> (32 - (r))); x1 ^= x0; }
    TFR(13) TFR(15) TFR(26) TFR(6)
    x0 += ks1; x1 += ks2 + 1u;
    TFR(17) TFR(29) TFR(16) TFR(24)
    x0 += ks2; x1 += ks0 + 2u;
    TFR(13) TFR(15) TFR(26) TFR(6)
    x0 += ks0; x1 += ks1 + 3u;
    TFR(17) TFR(29) TFR(16) TFR(24)
    x0 += ks1; x1 += ks2 + 4u;
    TFR(13) TFR(15) TFR(26) TFR(6)
    x0 += ks2; x1 += ks0 + 5u;
#undef TFR
}

// ---------------------------------------------------------------------------
// finalize: logit[t] = part0[t]+part1[t] + q[slot].bk2; softmax + gumbel
// argmax + top-2 gap (for cleanup). 4 lanes cooperate per slot.
// ---------------------------------------------------------------------------
__global__ __launch_bounds__(256)
void logits_finalize(const double* __restrict__ part,
                     const float* __restrict__ q, const float* __restrict__ bk2,
                     const int* __restrict__ mask,
                     float* __restrict__ out_logits, float* __restrict__ out_policy,
                     float* __restrict__ out_index, float* __restrict__ gaps)
{
    const int t    = blockIdx.x * 256 + threadIdx.x;   // 0..RM_-1
    const int slot = t >> 2;
    const int m    = t & 3;

    double dot = part[t] + part[RM_ + t];
    {
        const float4* qp = (const float4*)&q[(size_t)slot * F4_];
        const float4* bp = (const float4*)bk2;
        double qb = 0.0;
#pragma unroll
        for (int i = 0; i < 32; i++) {
            float4 a = qp[i], b = bp[i];
            qb += (double)a.x * b.x; qb += (double)a.y * b.y;
            qb += (double)a.z * b.z; qb += (double)a.w * b.w;
        }
        dot += qb;
    }

    const bool legal = (mask[t] != 0);

    double lmin = fmin(dot, __shfl_xor(dot, 1));
    lmin = fmin(lmin, __shfl_xor(lmin, 2));
    const double lm = legal ? dot : lmin;
    double lmax = fmax(lm, __shfl_xor(lm, 1));
    lmax = fmax(lmax, __shfl_xor(lmax, 2));
    const double e = legal ? exp(lm - lmax) : 0.0;
    double esum = e + __shfl_xor(e, 1);
    esum += __shfl_xor(esum, 2);
    const double policy = e / esum;

    out_logits[t] = (float)dot;
    out_policy[t] = (float)policy;

    const double sl = (policy > 0.0) ? log(policy) : -1e30;

    unsigned int x0 = 0u;
    unsigned int x1 = (unsigned int)t;
    threefry2x32_k42(x0, x1);
    const unsigned int bits = x0 ^ x1;

    const float f  = __uint_as_float(0x3f800000u | (bits >> 9)) - 1.0f;
    const float uf = fmaxf(1.17549435e-38f, f);
    const double g = -log(-log((double)uf));
    const double v = sl + g;

    int    best = m;
    double bv   = v;
    {
        double ov = __shfl_xor(bv, 1); int oi = __shfl_xor(best, 1);
        if (ov > bv || (ov == bv && oi < best)) { bv = ov; best = oi; }
        ov = __shfl_xor(bv, 2); oi = __shfl_xor(best, 2);
        if (ov > bv || (ov == bv && oi < best)) { bv = ov; best = oi; }
    }

    double a1 = fmax(v, __shfl_xor(v, 1));
    double b1 = fmin(v, __shfl_xor(v, 1));
    double a2 = __shfl_xor(a1, 2);
    double b2 = __shfl_xor(b1, 2);
    double top2 = (a1 >= a2) ? fmax(a2, b1) : fmax(a1, b2);
    double top1 = fmax(a1, a2);

    if (m == 0) {
        out_index[slot] = (float)best;
        gaps[slot] = (float)(top1 - top2);
    }
}

// ---------------------------------------------------------------------------
// near-tie cleanup, stage A: compact slot list (single block, LDS counter)
// ---------------------------------------------------------------------------
#define TAU_ 3e-3f

__global__ __launch_bounds__(1024)
void compact_kernel(const float* __restrict__ gaps,
                    int* __restrict__ cnt, int* __restrict__ list)
{
    __shared__ int c;
    if (threadIdx.x == 0) c = 0;
    __syncthreads();
    for (int s = threadIdx.x; s < R_; s += 1024) {
        if (gaps[s] < TAU_) list[atomicAdd(&c, 1)] = s;
    }
    __syncthreads();
    if (threadIdx.x == 0) *cnt = c;
}

// ---------------------------------------------------------------------------
// near-tie cleanup, stage B: exact f64 recompute, throughput-structured.
// ---------------------------------------------------------------------------
__global__ __launch_bounds__(256)
void cleanup2_kernel(const float* __restrict__ x, const float* __restrict__ moves,
                     const int* __restrict__ mask,
                     const float* __restrict__ Wq1, const float* __restrict__ bq1,
                     const float* __restrict__ Wq2, const float* __restrict__ bq2,
                     const float* __restrict__ Wk1, const float* __restrict__ bk1,
                     const float* __restrict__ Wk2, const float* __restrict__ bk2,
                     const int* __restrict__ cnt, const int* __restrict__ list,
                     float* __restrict__ out_index)
{
    __shared__ float  xs[512];
    __shared__ float  mvs[1024];        // 4 x 256 move rows
    __shared__ float  ws[16 * 256];     // staged weight chunk (16 KB)
    __shared__ double h1q[256];
    __shared__ double h1k[4][256];
    __shared__ double qv[128];
    __shared__ double kv[4][128];
    __shared__ double wred[8];

    const int j = threadIdx.x;
    const int n = *cnt;

    for (int ii = blockIdx.x; ii < n; ii += gridDim.x) {
        const int s = list[ii];
        __syncthreads();   // protect LDS reuse across slot iterations

        *(float2*)&xs[j * 2] = *(const float2*)&x[(size_t)s * F_ + j * 2];
        ((float4*)mvs)[j] = ((const float4*)&moves[(size_t)s * 4 * F2_])[j];

        // ---- h1q[j] = relu(x . Wq1[:,j] + bq1[j]) ----
        double a0 = 0.0, a1 = 0.0;
        for (int c0 = 0; c0 < 512; c0 += 16) {
            __syncthreads();
#pragma unroll
            for (int u = 0; u < 4; u++) {
                int idx = u * 256 + j;
                int r = idx >> 6, c4 = (idx & 63) * 4;
                *(float4*)&ws[r * 256 + c4] = *(const float4*)&Wq1[(size_t)(c0 + r) * F2_ + c4];
            }
            __syncthreads();
#pragma unroll
            for (int c = 0; c < 16; c += 2) {
                a0 += (double)xs[c0 + c]     * (double)ws[c * 256 + j];
                a1 += (double)xs[c0 + c + 1] * (double)ws[(c + 1) * 256 + j];
            }
        }
        h1q[j] = fmax(a0 + a1 + (double)bq1[j], 0.0);

        // ---- qv[j<128] = h1q . Wq2[:,j] + bq2[j] ----
        double q0 = 0.0, q1 = 0.0;
        for (int c0 = 0; c0 < 256; c0 += 32) {
            __syncthreads();
#pragma unroll
            for (int u = 0; u < 4; u++) {
                int idx = u * 256 + j;
                int r = idx >> 5, c4 = (idx & 31) * 4;
                *(float4*)&ws[r * 128 + c4] = *(const float4*)&Wq2[(size_t)(c0 + r) * F4_ + c4];
            }
            __syncthreads();
            if (j < 128) {
#pragma unroll
                for (int c = 0; c < 32; c += 2) {
                    q0 += h1q[c0 + c]     * (double)ws[c * 128 + j];
                    q1 += h1q[c0 + c + 1] * (double)ws[(c + 1) * 128 + j];
                }
            }
        }
        if (j < 128) qv[j] = q0 + q1 + (double)bq2[j];

        // ---- h1k[m][j] for all 4 moves ----
        double k0 = 0.0, k1 = 0.0, k2 = 0.0, k3 = 0.0;
        for (int c0 = 0; c0 < 256; c0 += 16) {
            __syncthreads();
#pragma unroll
            for (int u = 0; u < 4; u++) {
                int idx = u * 256 + j;
                int r = idx >> 6, c4 = (idx & 63) * 4;
                *(float4*)&ws[r * 256 + c4] = *(const float4*)&Wk1[(size_t)(c0 + r) * F2_ + c4];
            }
            __syncthreads();
#pragma unroll
            for (int c = 0; c < 16; c++) {
                double w = (double)ws[c * 256 + j];
                k0 += (double)mvs[0 * 256 + c0 + c] * w;
                k1 += (double)mvs[1 * 256 + c0 + c] * w;
                k2 += (double)mvs[2 * 256 + c0 + c] * w;
                k3 += (double)mvs[3 * 256 + c0 + c] * w;
            }
        }
        h1k[0][j] = fmax(k0 + (double)bk1[j], 0.0);
        h1k[1][j] = fmax(k1 + (double)bk1[j], 0.0);
        h1k[2][j] = fmax(k2 + (double)bk1[j], 0.0);
        h1k[3][j] = fmax(k3 + (double)bk1[j], 0.0);

        // ---- kv[m][jj] = h1k[m] . Wk2[:,jj] + bk2[jj] ----
        const int jj = j & 127, mh = j >> 7;
        double v0 = 0.0, v1 = 0.0;
        for (int c0 = 0; c0 < 256; c0 += 32) {
            __syncthreads();
#pragma unroll
            for (int u = 0; u < 4; u++) {
                int idx = u * 256 + j;
                int r = idx >> 5, c4 = (idx & 31) * 4;
                *(float4*)&ws[r * 128 + c4] = *(const float4*)&Wk2[(size_t)(c0 + r) * F4_ + c4];
            }
            __syncthreads();
#pragma unroll
            for (int c = 0; c < 32; c++) {
                double w = (double)ws[c * 128 + jj];
                v0 += h1k[mh][c0 + c]     * w;
                v1 += h1k[mh + 2][c0 + c] * w;
            }
        }
        kv[mh][jj]     = v0 + (double)bk2[jj];
        kv[mh + 2][jj] = v1 + (double)bk2[jj];
        __syncthreads();

        {
            const int w = j >> 6, l = j & 63;
            double d = qv[l] * kv[w][l] + qv[l + 64] * kv[w][l + 64];
#pragma unroll
            for (int o = 32; o; o >>= 1) d += __shfl_xor(d, o);
            if (l == 0) wred[w] = d;
        }
        __syncthreads();

        if (j == 0) {
            double dotS[4];
#pragma unroll
            for (int mv = 0; mv < 4; mv++) dotS[mv] = wred[mv];
            double lmin = dotS[0];
#pragma unroll
            for (int mv = 1; mv < 4; mv++) lmin = fmin(lmin, dotS[mv]);
            double lm[4]; bool lg[4];
            double lmax = -1e300;
#pragma unroll
            for (int mv = 0; mv < 4; mv++) {
                lg[mv] = (mask[(size_t)s * 4 + mv] != 0);
                lm[mv] = lg[mv] ? dotS[mv] : lmin;
                lmax = fmax(lmax, lm[mv]);
            }
            double e[4]; double esum = 0.0;
#pragma unroll
            for (int mv = 0; mv < 4; mv++) {
                e[mv] = lg[mv] ? exp(lm[mv] - lmax) : 0.0;
                esum += e[mv];
            }
            int best = -1; double bv = -1e308;
#pragma unroll
            for (int mv = 0; mv < 4; mv++) {
                double pol = e[mv] / esum;
                double sl = (pol > 0.0) ? log(pol) : -1e30;
                unsigned xx0 = 0u, xx1 = (unsigned)(s * 4 + mv);
                threefry2x32_k42(xx0, xx1);
                unsigned bits = xx0 ^ xx1;
                float fu = __uint_as_float(0x3f800000u | (bits >> 9)) - 1.0f;
                float uf = fmaxf(1.17549435e-38f, fu);
                double g = -log(-log((double)uf));
                double v = sl + g;
                if (v > bv) { bv = v; best = mv; }
            }
            out_index[s] = (float)best;
        }
    }
}

// ===========================================================================
// LEGACY FALLBACK (previous verified kernels) — used if d_ws is too small
// ===========================================================================
template<int KDIM>
__global__ __launch_bounds__(256, 3)
void mlp2_kernel(const float* __restrict__ A,
                 const float* __restrict__ W1, const float* __restrict__ b1,
                 const float* __restrict__ W2, const float* __restrict__ b2,
                 float* __restrict__ out)
{
    __shared__ float H[32][260];
    __shared__ float As[32][20];
    __shared__ float Bs[4096];

    const int tid  = threadIdx.x;
    const int row0 = blockIdx.x * 32;
    const int tx   = tid & 31;
    const int ty   = tid >> 5;

    float acc[4][8];
#pragma unroll
    for (int i = 0; i < 4; i++)
#pragma unroll
        for (int j = 0; j < 8; j++) acc[i][j] = 0.f;

    for (int k0 = 0; k0 < KDIM; k0 += 16) {
        {
            int r = tid >> 3;
            int c = (tid & 7) * 2;
            float2 v = *(const float2*)&A[(size_t)(row0 + r) * KDIM + k0 + c];
            *(float2*)&As[r][c] = v;
        }
        {
            int kk = tid >> 4;
            int c0 = (tid & 15) * 16;
            const float* src = &W1[(size_t)(k0 + kk) * F2_ + c0];
            float* dst = &Bs[kk * F2_ + c0];
#pragma unroll
            for (int j = 0; j < 4; j++) ((float4*)dst)[j] = ((const float4*)src)[j];
        }
        __syncthreads();
#pragma unroll
        for (int kk = 0; kk < 16; kk += 4) {
            float4 a[4];
#pragma unroll
            for (int i = 0; i < 4; i++) a[i] = *(const float4*)&As[ty * 4 + i][kk];
#pragma unroll
            for (int u = 0; u < 4; u++) {
                float4 w0 = *(const float4*)&Bs[(kk + u) * F2_ + tx * 8];
                float4 w1 = *(const float4*)&Bs[(kk + u) * F2_ + tx * 8 + 4];
#pragma unroll
                for (int i = 0; i < 4; i++) {
                    float av = ((const float*)&a[i])[u];
                    acc[i][0] += av * w0.x; acc[i][1] += av * w0.y;
                    acc[i][2] += av * w0.z; acc[i][3] += av * w0.w;
                    acc[i][4] += av * w1.x; acc[i][5] += av * w1.y;
                    acc[i][6] += av * w1.z; acc[i][7] += av * w1.w;
                }
            }
        }
        __syncthreads();
    }
    {
        float4 b1a = *(const float4*)&b1[tx * 8];
        float4 b1b = *(const float4*)&b1[tx * 8 + 4];
        const float bv[8] = {b1a.x, b1a.y, b1a.z, b1a.w, b1b.x, b1b.y, b1b.z, b1b.w};
#pragma unroll
        for (int i = 0; i < 4; i++) {
            float4 h0, h1;
            h0.x = fmaxf(acc[i][0] + bv[0], 0.f);
            h0.y = fmaxf(acc[i][1] + bv[1], 0.f);
            h0.z = fmaxf(acc[i][2] + bv[2], 0.f);
            h0.w = fmaxf(acc[i][3] + bv[3], 0.f);
            h1.x = fmaxf(acc[i][4] + bv[4], 0.f);
            h1.y = fmaxf(acc[i][5] + bv[5], 0.f);
            h1.z = fmaxf(acc[i][6] + bv[6], 0.f);
            h1.w = fmaxf(acc[i][7] + bv[7], 0.f);
            *(float4*)&H[ty * 4 + i][tx * 8]     = h0;
            *(float4*)&H[ty * 4 + i][tx * 8 + 4] = h1;
        }
    }
    __syncthreads();

    float acc2[4][4];
#pragma unroll
    for (int i = 0; i < 4; i++)
#pragma unroll
        for (int j = 0; j < 4; j++) acc2[i][j] = 0.f;

    for (int k0 = 0; k0 < F2_; k0 += 32) {
        {
            int kk = tid >> 3;
            int c0 = (tid & 7) * 16;
            const float* src = &W2[(size_t)(k0 + kk) * F4_ + c0];
            float* dst = &Bs[kk * F4_ + c0];
#pragma unroll
            for (int j = 0; j < 4; j++) ((float4*)dst)[j] = ((const float4*)src)[j];
        }
        __syncthreads();
#pragma unroll
        for (int kk = 0; kk < 32; kk += 4) {
            float4 h[4];
#pragma unroll
            for (int i = 0; i < 4; i++) h[i] = *(const float4*)&H[ty * 4 + i][k0 + kk];
#pragma unroll
            for (int u = 0; u < 4; u++) {
                float4 w = *(const float4*)&Bs[(kk + u) * F4_ + tx * 4];
#pragma unroll
                for (int i = 0; i < 4; i++) {
                    float hv = ((const float*)&h[i])[u];
                    acc2[i][0] += hv * w.x; acc2[i][1] += hv * w.y;
                    acc2[i][2] += hv * w.z; acc2[i][3] += hv * w.w;
                }
            }
        }
        __syncthreads();
    }
    {
        float4 bb = *(const float4*)&b2[tx * 4];
#pragma unroll
        for (int i = 0; i < 4; i++) {
            float4 o;
            o.x = acc2[i][0] + bb.x;
            o.y = acc2[i][1] + bb.y;
            o.z = acc2[i][2] + bb.z;
            o.w = acc2[i][3] + bb.w;
            *(float4*)&out[(size_t)(row0 + ty * 4 + i) * F4_ + tx * 4] = o;
        }
    }
}

__global__ __launch_bounds__(256)
void logits_sample_kernel(const float* __restrict__ Q, const float* __restrict__ Kv,
                          const int* __restrict__ mask,
                          float* __restrict__ out_logits, float* __restrict__ out_policy,
                          float* __restrict__ out_index)
{
    const int t    = blockIdx.x * 256 + threadIdx.x;
    const int slot = t >> 2;
    const int m    = t & 3;

    const float4* qp = (const float4*)&Q[(size_t)slot * F4_];
    const float4* kp = (const float4*)&Kv[(size_t)t * F4_];
    double dot = 0.0;
#pragma unroll
    for (int i = 0; i < 32; i++) {
        float4 a = qp[i], b = kp[i];
        dot += (double)a.x * b.x; dot += (double)a.y * b.y;
        dot += (double)a.z * b.z; dot += (double)a.w * b.w;
    }

    const bool legal = (mask[t] != 0);

    double lmin = fmin(dot, __shfl_xor(dot, 1));
    lmin = fmin(lmin, __shfl_xor(lmin, 2));
    const double lm = legal ? dot : lmin;
    double lmax = fmax(lm, __shfl_xor(lm, 1));
    lmax = fmax(lmax, __shfl_xor(lmax, 2));
    const double e = legal ? exp(lm - lmax) : 0.0;
    double esum = e + __shfl_xor(e, 1);
    esum += __shfl_xor(esum, 2);
    const double policy = e / esum;

    out_logits[t] = (float)dot;
    out_policy[t] = (float)policy;

    const double sl = (policy > 0.0) ? log(policy) : -1e30;

    unsigned int x0 = 0u;
    unsigned int x1 = (unsigned int)t;
    threefry2x32_k42(x0, x1);
    const unsigned int bits = x0 ^ x1;

    const float f  = __uint_as_float(0x3f800000u | (bits >> 9)) - 1.0f;
    const float uf = fmaxf(1.17549435e-38f, f);
    const double g = -log(-log((double)uf));
    const double v = sl + g;

    int    best = m;
    double bv   = v;
    {
        double ov = __shfl_xor(bv, 1); int oi = __shfl_xor(best, 1);
        if (ov > bv || (ov == bv && oi < best)) { bv = ov; best = oi; }
        ov = __shfl_xor(bv, 2); oi = __shfl_xor(best, 2);
        if (ov > bv || (ov == bv && oi < best)) { bv = ov; best = oi; }
    }
    if (m == 0) out_index[slot] = (float)best;
}

__global__ __launch_bounds__(256, 3)
void proj_kernel(const float* __restrict__ moves, const float* __restrict__ idxf,
                 const float* __restrict__ Wp, const float* __restrict__ bp,
                 const float* __restrict__ x, const int* __restrict__ atype,
                 float* __restrict__ out_ar, float* __restrict__ out_proj)
{
    __shared__ float As[32][260];
    __shared__ float Bs[32 * 128];

    const int tid  = threadIdx.x;
    const int row0 = blockIdx.x * 32;
    const int col0 = blockIdx.y * 128;
    const int tx   = tid & 31;
    const int ty   = tid >> 5;

#pragma unroll
    for (int it = 0; it < 8; it++) {
        int r = (tid >> 6) + it * 4;
        int c = (tid & 63) * 4;
        int slot = row0 + r;
        int mi = (int)idxf[slot];
        float4 v = *(const float4*)&moves[((size_t)slot * 4 + mi) * F2_ + c];
        *(float4*)&As[r][c] = v;
    }
    __syncthreads();

    float acc[4][4];
#pragma unroll
    for (int i = 0; i < 4; i++)
#pragma unroll
        for (int j = 0; j < 4; j++) acc[i][j] = 0.f;

    for (int k0 = 0; k0 < F2_; k0 += 32) {
        {
            int kk = tid >> 3;
            int c0 = (tid & 7) * 16;
            const float* src = &Wp[(size_t)(k0 + kk) * F_ + col0 + c0];
            float* dst = &Bs[kk * 128 + c0];
#pragma unroll
            for (int j = 0; j < 4; j++) ((float4*)dst)[j] = ((const float4*)src)[j];
        }
        __syncthreads();
#pragma unroll
        for (int kk = 0; kk < 32; kk += 4) {
            float4 h[4];
#pragma unroll
            for (int i = 0; i < 4; i++) h[i] = *(const float4*)&As[ty * 4 + i][k0 + kk];
#pragma unroll
            for (int u = 0; u < 4; u++) {
                float4 w = *(const float4*)&Bs[(kk + u) * 128 + tx * 4];
#pragma unroll
                for (int i = 0; i < 4; i++) {
                    float hv = ((const float*)&h[i])[u];
                    acc[i][0] += hv * w.x; acc[i][1] += hv * w.y;
                    acc[i][2] += hv * w.z; acc[i][3] += hv * w.w;
                }
            }
        }
        __syncthreads();
    }

    float4 bb = *(const float4*)&bp[col0 + tx * 4];
#pragma unroll
    for (int i = 0; i < 4; i++) {
        int row = row0 + ty * 4 + i;
        float4 p;
        p.x = acc[i][0] + bb.x;
        p.y = acc[i][1] + bb.y;
        p.z = acc[i][2] + bb.z;
        p.w = acc[i][3] + bb.w;
        size_t off = (size_t)row * F_ + col0 + tx * 4;
        *(float4*)&out_proj[off] = p;
        float4 a = *(const float4*)&x[off];
        bool valid = (atype[row] == 0);
        float4 r4;
        r4.x = valid ? a.x + p.x : a.x;
        r4.y = valid ? a.y + p.y : a.y;
        r4.z = valid ? a.z + p.z : a.z;
        r4.w = valid ? a.w + p.w : a.w;
        *(float4*)&out_ar[off] = r4;
    }
}

// ---------------------------------------------------------------------------
extern "C" void kernel_launch(void* const* d_in, const int* in_sizes, int n_in,
                              void* d_out, int out_size, void* d_ws, size_t ws_size,
                              hipStream_t stream)
{
    (void)in_sizes; (void)n_in; (void)out_size;

    const int*   atype = (const int*)d_in[0];
    const float* x     = (const float*)d_in[1];
    const float* moves = (const float*)d_in[2];
    const int*   mask  = (const int*)d_in[3];
    const float* Wq1   = (const float*)d_in[4];
    const float* bq1   = (const float*)d_in[5];
    const float* Wq2   = (const float*)d_in[6];
    const float* bq2   = (const float*)d_in[7];
    const float* Wk1   = (const float*)d_in[8];
    const float* bk1   = (const float*)d_in[9];
    const float* Wk2   = (const float*)d_in[10];
    const float* bk2   = (const float*)d_in[11];
    const float* Wp    = (const float*)d_in[12];
    const float* bp    = (const float*)d_in[13];

    float* out_logits = (float*)d_out;                   // [R_,4]
    float* out_policy = out_logits + RM_;                // [R_,4]
    float* out_index  = out_policy + RM_;                // [R_,1]
    float* out_ar     = out_index + R_;                  // [R_,512]
    float* out_proj   = out_ar + (size_t)R_ * F_;        // [R_,512]

    // Workspace: split-bf16 weight planes (1.5 MB) + gaps (128 KB)
    const size_t WS_NEED = (size_t)786432 * 2 + (size_t)R_ * 4;   // 1,703,936 B

    if (d_ws != nullptr && ws_size >= WS_NEED) {
        unsigned short* wq1h = (unsigned short*)d_ws;    // [256][512]
        unsigned short* wq1l = wq1h + 131072;
        unsigned short* wq2h = wq1l + 131072;            // [128][256]
        unsigned short* wq2l = wq2h + 32768;
        unsigned short* wk1h = wq2l + 32768;             // [256][256]
        unsigned short* wk1l = wk1h + 65536;
        unsigned short* wk2h = wk1l + 65536;             // [256][128]
        unsigned short* wk2l = wk2h + 32768;
        unsigned short* wph  = wk2l + 32768;             // [512][256]
        unsigned short* wpl  = wph + 131072;
        float* gaps = (float*)(wpl + 131072);

        // scratch carved out of d_out regions that proj overwrites last:
        float*  Hq   = out_ar;                         // [32768][256]  (32 MB)
        float*  qv   = out_ar + 8388608;               // [32768][128]  (16 MB)
        float*  uv   = out_proj;                       // [32768][256]  (32 MB)
        double* part = (double*)(out_ar + 12582912);   // [2][131072] f64 (2 MB)
        int* cl_cnt  = (int*)(out_ar + 13631488);
        int* cl_list = cl_cnt + 16;

        // ---- repack weights to [N][K] bf16 hi/lo planes ----
        repack_kernel<true ><<<512, 256, 0, stream>>>(Wq1, F2_, 9, wq1h, wq1l);
        repack_kernel<true ><<<128, 256, 0, stream>>>(Wq2, F4_, 8, wq2h, wq2l);
        repack_kernel<true ><<<256, 256, 0, stream>>>(Wk1, F2_, 8, wk1h, wk1l);
        repack_kernel<false><<<128, 256, 0, stream>>>(Wk2, F4_, 7, wk2h, wk2l);
        repack_kernel<true ><<<512, 256, 0, stream>>>(Wp,  F_,  8, wph,  wpl);

        // ---- Q path ----
        dim3 g1(R_ / 128, 2);
        gemm_bf16s<512, 256, true,  false, false><<<g1, 256, 0, stream>>>(
            x, wq1h, wq1l, bq1, Hq, nullptr, nullptr, nullptr, nullptr, nullptr, nullptr, nullptr);
        dim3 g2(R_ / 128, 1);
        gemm_bf16s<256, 128, false, false, false><<<g2, 256, 0, stream>>>(
            Hq, wq2h, wq2l, bq2, qv, nullptr, nullptr, nullptr, nullptr, nullptr, nullptr, nullptr);
        dim3 g3(R_ / 128, 2);
        gemm_bf16s<128, 256, false, false, false><<<g3, 256, 0, stream>>>(
            qv, wk2h, wk2l, nullptr, uv, nullptr, nullptr, nullptr, nullptr, nullptr, nullptr, nullptr);

        // ---- fused K path: gemm + per-row u-dot -> logit partials ----
        dim3 gk(RM_ / 128, 2);
        gemm_bf16s<256, 256, true, false, true><<<gk, 256, 0, stream>>>(
            moves, wk1h, wk1l, bk1, nullptr, nullptr, nullptr, nullptr, nullptr, nullptr, uv, part);

        // ---- finalize: softmax + gumbel sample + gaps ----
        logits_finalize<<<RM_ / 256, 256, 0, stream>>>(
            part, qv, bk2, mask, out_logits, out_policy, out_index, gaps);

        // ---- near-tie exact recompute ----
        compact_kernel<<<1, 1024, 0, stream>>>(gaps, cl_cnt, cl_list);
        cleanup2_kernel<<<128, 256, 0, stream>>>(
            x, moves, mask, Wq1, bq1, Wq2, bq2, Wk1, bk1, Wk2, bk2,
            cl_cnt, cl_list, out_index);

        // ---- gather + projection + ar_out epilogue ----
        dim3 gp(R_ / 128, 4);
        gemm_bf16s<256, 512, false, true, false><<<gp, 256, 0, stream>>>(
            nullptr, wph, wpl, bp, out_proj, out_index, moves, x, atype, out_ar, nullptr, nullptr);
    } else {
        // -------- legacy fp32 path (previous verified kernel) --------
        float* Q  = out_proj;
        float* Kv = out_ar;

        mlp2_kernel<F_><<<R_ / 32, 256, 0, stream>>>(x, Wq1, bq1, Wq2, bq2, Q);
        mlp2_kernel<F2_><<<RM_ / 32, 256, 0, stream>>>(moves, Wk1, bk1, Wk2, bk2, Kv);
        logits_sample_kernel<<<RM_ / 256, 256, 0, stream>>>(Q, Kv, mask,
                                                            out_logits, out_policy, out_index);
        dim3 pgrid(R_ / 32, 4);
        proj_kernel<<<pgrid, 256, 0, stream>>>(moves, out_index, Wp, bp, x, atype,
                                               out_ar, out_proj);
    }
}